// Round 4
// baseline (1897.600 us; speedup 1.0000x reference)
//
#include <hip/hip_runtime.h>
#include <math.h>

#define N_NODES 49152
#define BGRAPH  64
#define MAXN_   768
#define NEDGE   491520
#define DD      128
#define CC      160
#define DI_     320
#define DS_     128
#define DTR_    10

__device__ __forceinline__ float sigm(float x) { return 1.f / (1.f + __expf(-x)); }
__device__ __forceinline__ float softplusf(float x) {
    return (x > 20.f) ? x : log1pf(__expf(x));
}

// block-wide sum: all threads get result. blockDim multiple of 64.
__device__ __forceinline__ float blkSum(float v, float* scratch) {
    __syncthreads();
    #pragma unroll
    for (int off = 32; off > 0; off >>= 1) v += __shfl_down(v, off);
    if ((threadIdx.x & 63) == 0) scratch[threadIdx.x >> 6] = v;
    __syncthreads();
    int nw = blockDim.x >> 6;
    float s = 0.f;
    for (int i = 0; i < nw; ++i) s += scratch[i];
    return s;
}

__device__ __forceinline__ float blkMax(float v, float* scratch) {
    __syncthreads();
    #pragma unroll
    for (int off = 32; off > 0; off >>= 1) v = fmaxf(v, __shfl_down(v, off));
    if ((threadIdx.x & 63) == 0) scratch[threadIdx.x >> 6] = v;
    __syncthreads();
    int nw = blockDim.x >> 6;
    float s = scratch[0];
    for (int i = 1; i < nw; ++i) s = fmaxf(s, scratch[i]);
    return s;
}

// ---------------- CSR build: histogram / scan / scatter -----------------------
__global__ void k_hist(const int* __restrict__ dst, int* __restrict__ cnt) {
    int e = blockIdx.x * 256 + threadIdx.x;
    if (e < NEDGE) atomicAdd(&cnt[dst[e]], 1);
}

__global__ void k_scan(const int* __restrict__ cnt, int* __restrict__ off,
                       int* __restrict__ cursor) {
    __shared__ int part[256];
    const int t = threadIdx.x;           // 256 threads, 192 nodes each
    const int base = t * 192;
    int s = 0;
    for (int i = 0; i < 192; ++i) s += cnt[base + i];
    part[t] = s;
    __syncthreads();
    if (t == 0) {
        int run = 0;
        for (int i = 0; i < 256; ++i) { int v = part[i]; part[i] = run; run += v; }
    }
    __syncthreads();
    int run = part[t];
    for (int i = 0; i < 192; ++i) {
        int idx = base + i;
        off[idx] = run;
        cursor[idx] = run;
        run += cnt[idx];
    }
    if (t == 255) off[N_NODES] = run;    // == NEDGE
}

__global__ void k_scatter(const int* __restrict__ dst, int* __restrict__ cursor,
                          int* __restrict__ eids) {
    int e = blockIdx.x * 256 + threadIdx.x;
    if (e < NEDGE) {
        int pos = atomicAdd(&cursor[dst[e]], 1);
        eids[pos] = e;
    }
}

// ---------------- K2': gather-style gated aggregation (no atomics) ------------
__global__ void k_agg(const float* __restrict__ x, const float* __restrict__ ea,
                      const int* __restrict__ src,
                      const int* __restrict__ off, const int* __restrict__ eids,
                      const float* __restrict__ We, const float* __restrict__ be,
                      float* __restrict__ agg)
{
    const int n = blockIdx.x;
    const int d = threadIdx.x;   // 128
    const float w00 = We[d],           w01 = We[128 + d],       bb0 = be[d];
    const float w10 = We[256 + d],     w11 = We[256 + 128 + d], bb1 = be[128 + d];
    const float w20 = We[512 + d],     w21 = We[512 + 128 + d], bb2 = be[256 + d];
    const int beg = off[n], end = off[n + 1];
    float acc0 = 0.f, acc1 = 0.f, acc2 = 0.f;
    for (int i = beg; i < end; ++i) {
        int e = eids[i];
        int s = src[e];
        float ea0 = ea[2 * e], ea1 = ea[2 * e + 1];
        float xv = x[s * DD + d];
        acc0 += xv * sigm(ea0 * w00 + ea1 * w01 + bb0);
        acc1 += xv * sigm(ea0 * w10 + ea1 * w11 + bb1);
        acc2 += xv * sigm(ea0 * w20 + ea1 * w21 + bb2);
    }
    agg[              n * DD + d] = acc0;
    agg[N_NODES * DD + n * DD + d] = acc1;
    agg[2 * N_NODES * DD + n * DD + d] = acc2;
}

// ---------------- K3: xs_i = relu((x+agg_i)@Wx_i + bx_i), in-place over agg ----
__global__ void k_xs(const float* __restrict__ x, float* __restrict__ agg,
                     const float* __restrict__ Wx, const float* __restrict__ bx)
{
    const int i  = blockIdx.y;
    const int n0 = blockIdx.x * 16;
    const int j  = threadIdx.x;  // 128
    __shared__ float inL[16 * 128];
    float* aggi = agg + i * (N_NODES * DD);
    #pragma unroll
    for (int r = 0; r < 16; ++r)
        inL[r * 128 + j] = x[(n0 + r) * DD + j] + aggi[(n0 + r) * DD + j];
    __syncthreads();
    float acc[16];
    #pragma unroll
    for (int r = 0; r < 16; ++r) acc[r] = 0.f;
    const float* W = Wx + i * (DD * DD);
    for (int k = 0; k < 128; ++k) {
        float w = W[k * 128 + j];
        #pragma unroll
        for (int r = 0; r < 16; ++r) acc[r] += inL[r * 128 + k] * w;
    }
    float bb = bx[i * 128 + j];
    #pragma unroll
    for (int r = 0; r < 16; ++r) {
        float v = acc[r] + bb;
        aggi[(n0 + r) * DD + j] = v > 0.f ? v : 0.f;
    }
}

// ---------------- K4: P0 = xp @ wm_w0[:160] + b0  (step-invariant) ------------
__global__ void k_p0(const float* __restrict__ x, const float* __restrict__ lpe,
                     const float* __restrict__ rwse, const float* __restrict__ w0,
                     const float* __restrict__ b0, float* __restrict__ P0)
{
    const int n0 = blockIdx.x * 16;
    const int j  = threadIdx.x;  // 192
    __shared__ float inL[16 * 160];
    for (int idx = j; idx < 16 * 160; idx += 192) {
        int r = idx / 160, k = idx - r * 160;
        int n = n0 + r;
        float v;
        if (k < 128)      v = x[n * 128 + k];
        else if (k < 144) v = lpe[n * 16 + (k - 128)];
        else              v = rwse[n * 16 + (k - 144)];
        inL[idx] = v;
    }
    __syncthreads();
    if (j < 160) {
        float acc[16];
        #pragma unroll
        for (int r = 0; r < 16; ++r) acc[r] = 0.f;
        for (int k = 0; k < 160; ++k) {
            float w = w0[k * 160 + j];
            #pragma unroll
            for (int r = 0; r < 16; ++r) acc[r] += inL[r * 160 + k] * w;
        }
        float bb = b0[j];
        #pragma unroll
        for (int r = 0; r < 16; ++r) P0[(n0 + r) * 160 + j] = acc[r] + bb;
    }
}

// ---------------- K6: per-row MLP -> attention scores -------------------------
__global__ void k_mlp(const float* __restrict__ P0, const float* __restrict__ hw0,
                      const float* __restrict__ w1, const float* __restrict__ b1,
                      const float* __restrict__ w2, const float* __restrict__ b2,
                      const float* __restrict__ w3, const float* __restrict__ b3,
                      float* __restrict__ scores)
{
    const int n0 = blockIdx.x * 16;
    const int b  = n0 / MAXN_;      // 16 | 768, so uniform per block
    const int j  = threadIdx.x;     // 192
    __shared__ float bufA[16 * 160];
    __shared__ float bufB[16 * 160];
    __shared__ float red[192];
    // a1 = relu(P0 + hw0[b])
    for (int idx = j; idx < 16 * 160; idx += 192) {
        int r = idx / 160, k = idx - r * 160;
        float v = P0[(n0 + r) * 160 + k] + hw0[b * 160 + k];
        bufA[idx] = v > 0.f ? v : 0.f;
    }
    __syncthreads();
    if (j < 160) {  // a2 = relu(a1@w1+b1)
        float acc[16];
        #pragma unroll
        for (int r = 0; r < 16; ++r) acc[r] = 0.f;
        for (int k = 0; k < 160; ++k) {
            float w = w1[k * 160 + j];
            #pragma unroll
            for (int r = 0; r < 16; ++r) acc[r] += bufA[r * 160 + k] * w;
        }
        float bb = b1[j];
        #pragma unroll
        for (int r = 0; r < 16; ++r) {
            float v = acc[r] + bb;
            bufB[r * 160 + j] = v > 0.f ? v : 0.f;
        }
    }
    __syncthreads();
    if (j < 160) {  // a3 = relu(a2@w2+b2)
        float acc[16];
        #pragma unroll
        for (int r = 0; r < 16; ++r) acc[r] = 0.f;
        for (int k = 0; k < 160; ++k) {
            float w = w2[k * 160 + j];
            #pragma unroll
            for (int r = 0; r < 16; ++r) acc[r] += bufB[r * 160 + k] * w;
        }
        float bb = b2[j];
        #pragma unroll
        for (int r = 0; r < 16; ++r) {
            float v = acc[r] + bb;
            bufA[r * 160 + j] = v > 0.f ? v : 0.f;
        }
    }
    __syncthreads();
    {   // score = a3 . w3 + b3
        int r = j / 12, lane = j - r * 12;   // 16 rows x 12 threads
        float p = 0.f;
        for (int k = lane; k < 160; k += 12) p += bufA[r * 160 + k] * w3[k];
        red[j] = p;
    }
    __syncthreads();
    if (j < 16) {
        float s = 0.f;
        #pragma unroll
        for (int i = 0; i < 12; ++i) s += red[j * 12 + i];
        scores[n0 + j] = s + b3[0];
    }
}

// ---------------- K7: per-graph softmax + t + GRU + hw0_next ------------------
__global__ void k_graph(const float* __restrict__ scores,
                        const float* __restrict__ x, const float* __restrict__ lpe,
                        const float* __restrict__ rwse,
                        const float* __restrict__ Wi, const float* __restrict__ Wh,
                        const float* __restrict__ bi, const float* __restrict__ bh,
                        const float* __restrict__ w0h,
                        float* __restrict__ h, float* __restrict__ hw0,
                        float* __restrict__ tok, int step)
{
    const int b   = blockIdx.x;
    const int tid = threadIdx.x;  // 256
    __shared__ float eL[MAXN_];
    __shared__ float tL[160];
    __shared__ float hL[160];
    __shared__ float hN[160];
    __shared__ float red[8];
    const float inv_sqrt_d = 0.08838834764831845f;  // 128^-0.5

    float m = -1e30f;
    for (int i = tid; i < MAXN_; i += 256) {
        float q = scores[b * MAXN_ + i] * inv_sqrt_d;
        eL[i] = q;
        m = fmaxf(m, q);
    }
    m = blkMax(m, red);
    float s = 0.f;
    for (int i = tid; i < MAXN_; i += 256) {
        float e = __expf(eL[i] - m);
        eL[i] = e;
        s += e;
    }
    if (tid < 160) hL[tid] = h[b * 160 + tid];
    float S = blkSum(s, red);
    float scale = 1.f / (S * (float)MAXN_);
    // t = sum_i alpha_i * xp_i / MAXN
    if (tid < 160) {
        const int c = tid;
        float acc = 0.f;
        for (int i = 0; i < MAXN_; ++i) {
            int n = b * MAXN_ + i;
            float v;
            if (c < 128)      v = x[n * 128 + c];
            else if (c < 144) v = lpe[n * 16 + (c - 128)];
            else              v = rwse[n * 16 + (c - 144)];
            acc += eL[i] * v;
        }
        float tv = acc * scale;
        tL[c] = tv;
        tok[b * 640 + step * 160 + c] = tv;
    }
    __syncthreads();
    // GRU
    if (tid < 160) {
        const int c = tid;
        float gr = bi[c], gz = bi[160 + c], gn = bi[320 + c];
        float hr = bh[c], hz = bh[160 + c], hn = bh[320 + c];
        for (int k = 0; k < 160; ++k) {
            float tv = tL[k], hv = hL[k];
            gr += tv * Wi[k * 480 + c];
            gz += tv * Wi[k * 480 + 160 + c];
            gn += tv * Wi[k * 480 + 320 + c];
            hr += hv * Wh[k * 480 + c];
            hz += hv * Wh[k * 480 + 160 + c];
            hn += hv * Wh[k * 480 + 320 + c];
        }
        float r = sigm(gr + hr);
        float z = sigm(gz + hz);
        float n = tanhf(gn + r * hn);
        float hnew = (1.f - z) * n + z * hL[c];
        hN[c] = hnew;
        h[b * 160 + c] = hnew;
    }
    __syncthreads();
    // hw0_next = h_new @ wm_w0[160:,:]
    if (tid < 160) {
        const int j = tid;
        float acc = 0.f;
        for (int k = 0; k < 160; ++k) acc += hN[k] * w0h[k * 160 + j];
        hw0[b * 160 + j] = acc;
    }
}

// ---------------- K9: mamba-ish part, one block per graph, t=3 output only ----
__global__ void k_mamba(const float* __restrict__ tok,
                        const float* __restrict__ Win, const float* __restrict__ convw,
                        const float* __restrict__ convb,
                        const float* __restrict__ Wx, const float* __restrict__ Wdt,
                        const float* __restrict__ bdt,
                        const float* __restrict__ Alog, const float* __restrict__ Dp,
                        const float* __restrict__ Wout,
                        const float* __restrict__ lng, const float* __restrict__ lnb,
                        float* __restrict__ mo_last)
{
    const int b   = blockIdx.x;
    const int tid = threadIdx.x;  // 256
    __shared__ float tokL[640];
    __shared__ float xpre[1280];
    __shared__ float xmL[1280];
    __shared__ float z3L[320];
    __shared__ float dtrL[40];
    __shared__ float BmL[512];
    __shared__ float Cm3L[128];
    __shared__ float dtL[1280];
    __shared__ float y3L[320];
    __shared__ float moL[160];
    __shared__ float red[8];

    for (int i = tid; i < 640; i += 256) tokL[i] = tok[b * 640 + i];
    __syncthreads();
    // xm_pre = tok @ Win[:, :320] ; z3 = tok[3] @ Win[:, 320:]
    for (int o = tid; o < 1280; o += 256) {
        int t = o / 320, d = o - t * 320;
        float acc = 0.f;
        for (int k = 0; k < 160; ++k) acc += tokL[t * 160 + k] * Win[k * 640 + d];
        xpre[o] = acc;
    }
    for (int d = tid; d < 320; d += 256) {
        float acc = 0.f;
        for (int k = 0; k < 160; ++k) acc += tokL[480 + k] * Win[k * 640 + 320 + d];
        z3L[d] = acc;
    }
    __syncthreads();
    // causal conv + silu
    for (int o = tid; o < 1280; o += 256) {
        int t = o / 320, d = o - t * 320;
        float acc = convb[d];
        #pragma unroll
        for (int k = 0; k < 4; ++k) {
            int tt = t + k - 3;
            if (tt >= 0) acc += xpre[tt * 320 + d] * convw[d * 4 + k];
        }
        xmL[o] = acc * sigm(acc);
    }
    __syncthreads();
    // dbl = xm @ Wx : dtr(4x10), Bm(4x128), Cm(t=3 only, 128)
    for (int o = tid; o < 680; o += 256) {
        int t, col;
        if (o < 40)       { t = o / 10; col = o - t * 10; }
        else if (o < 552) { int i = o - 40; t = i >> 7; col = 10 + (i & 127); }
        else              { t = 3; col = 138 + (o - 552); }
        float acc = 0.f;
        for (int k = 0; k < 320; ++k) acc += xmL[t * 320 + k] * Wx[k * 266 + col];
        if (o < 40)       dtrL[o] = acc;
        else if (o < 552) BmL[o - 40] = acc;
        else              Cm3L[o - 552] = acc;
    }
    __syncthreads();
    // dt = softplus(dtr @ Wdt + bdt)
    for (int o = tid; o < 1280; o += 256) {
        int t = o / 320, d = o - t * 320;
        float acc = bdt[d];
        #pragma unroll
        for (int r = 0; r < 10; ++r) acc += dtrL[t * 10 + r] * Wdt[r * 320 + d];
        dtL[o] = softplusf(acc);
    }
    __syncthreads();
    // scan over T=4, keep only y at t=3; wave w handles dim d, lane handles 2 states
    {
        int w = tid >> 6, lane = tid & 63;
        for (int dbase = 0; dbase < 320; dbase += 4) {
            int d = dbase + w;
            float A0 = -__expf(Alog[d * 128 + lane]);
            float A1 = -__expf(Alog[d * 128 + 64 + lane]);
            float s0 = 0.f, s1 = 0.f;
            #pragma unroll
            for (int t = 0; t < 4; ++t) {
                float dtv = dtL[t * 320 + d];
                float xv  = xmL[t * 320 + d];
                float c0  = dtv * xv;
                s0 = s0 * __expf(dtv * A0) + c0 * BmL[t * 128 + lane];
                s1 = s1 * __expf(dtv * A1) + c0 * BmL[t * 128 + 64 + lane];
            }
            float contrib = s0 * Cm3L[lane] + s1 * Cm3L[64 + lane];
            #pragma unroll
            for (int off = 32; off > 0; off >>= 1) contrib += __shfl_down(contrib, off);
            if (lane == 0) {
                float y  = contrib + Dp[d] * xmL[3 * 320 + d];
                float zz = z3L[d];
                y3L[d] = y * (zz * sigm(zz));
            }
        }
    }
    __syncthreads();
    // mo = LN(y3 @ Wout)
    if (tid < 160) {
        float acc = 0.f;
        for (int d = 0; d < 320; ++d) acc += y3L[d] * Wout[d * 160 + tid];
        moL[tid] = acc;
    }
    float v  = (tid < 160) ? moL[tid] : 0.f;   // moL write is own-thread; blkSum barriers cover others
    float sm = blkSum(v, red);
    float sq = blkSum(v * v, red);
    float mu  = sm / 160.f;
    float var = sq / 160.f - mu * mu;
    if (tid < 160)
        mo_last[b * 160 + tid] = (moL[tid] - mu) * rsqrtf(var + 1e-5f) * lng[tid] + lnb[tid];
}

// ---------------- K10: merge MLP + two LayerNorms -> out ----------------------
// One wave per 8-row tile. Lane l owns output cols {2l, 2l+1}; full K per lane
// (no K-slice reduce). 16 accumulators/thread -> no scratch spill (R3 lesson:
// 8x8 tile = 128 accs spilled ~450 MB to scratch). LN stats via 64-lane
// butterfly. Only 2 barriers (staging syncs).
__global__ __launch_bounds__(64) void k_final(
        const float* __restrict__ x, const float* __restrict__ xs,
        const int* __restrict__ batch, const float* __restrict__ mo_last,
        const float* __restrict__ w0, const float* __restrict__ b0,
        const float* __restrict__ g0, const float* __restrict__ beta0,
        const float* __restrict__ w1, const float* __restrict__ b1,
        const float* __restrict__ lng, const float* __restrict__ lnb,
        float* __restrict__ out)
{
    const int n0 = blockIdx.x * 8;
    const int l  = threadIdx.x;      // 64
    const int c0 = l * 2;
    __shared__ float catT[544 * 8];  // [k][r]
    __shared__ float hmR[8 * 128];   // [r][k]

    // stage catT[k*8+r] = cat[row n0+r][col k]
    for (int idx = l; idx < 544 * 8; idx += 64) {
        int r = idx & 7, k = idx >> 3;
        int n = n0 + r;
        float v;
        if (k < 384) v = xs[(k >> 7) * (N_NODES * 128) + n * 128 + (k & 127)];
        else         v = mo_last[batch[n] * 160 + (k - 384)];
        catT[idx] = v;
    }
    __syncthreads();

    // ---- GEMM1: acc[r][c] = sum_k cat[r][k] * w0[k][c0+c] ----
    float acc[8][2];
    #pragma unroll
    for (int r = 0; r < 8; ++r) { acc[r][0] = 0.f; acc[r][1] = 0.f; }
    #pragma unroll 4
    for (int k = 0; k < 544; ++k) {
        float4 ca = *(const float4*)&catT[k * 8];
        float4 cb = *(const float4*)&catT[k * 8 + 4];
        float2 w  = *(const float2*)&w0[k * 128 + c0];
        float cr[8] = {ca.x, ca.y, ca.z, ca.w, cb.x, cb.y, cb.z, cb.w};
        #pragma unroll
        for (int r = 0; r < 8; ++r) {
            acc[r][0] += cr[r] * w.x;
            acc[r][1] += cr[r] * w.y;
        }
    }

    // ---- LN1 + relu (per row over 128 cols), write hmR ----
    {
        float2 bv = *(const float2*)&b0[c0];
        float2 gv = *(const float2*)&g0[c0];
        float2 tv = *(const float2*)&beta0[c0];
        float rs[8], rq[8];
        #pragma unroll
        for (int r = 0; r < 8; ++r) {
            float v0 = acc[r][0] + bv.x;
            float v1 = acc[r][1] + bv.y;
            acc[r][0] = v0; acc[r][1] = v1;
            rs[r] = v0 + v1;
            rq[r] = v0 * v0 + v1 * v1;
        }
        #pragma unroll
        for (int m = 1; m <= 32; m <<= 1)
            #pragma unroll
            for (int r = 0; r < 8; ++r) {
                rs[r] += __shfl_xor(rs[r], m);
                rq[r] += __shfl_xor(rq[r], m);
            }
        #pragma unroll
        for (int r = 0; r < 8; ++r) {
            float mu  = rs[r] * (1.f / 128.f);
            float var = rq[r] * (1.f / 128.f) - mu * mu;
            float rv  = rsqrtf(var + 1e-5f);
            float n0v = (acc[r][0] - mu) * rv * gv.x + tv.x;
            float n1v = (acc[r][1] - mu) * rv * gv.y + tv.y;
            n0v = n0v > 0.f ? n0v : 0.f;
            n1v = n1v > 0.f ? n1v : 0.f;
            *(float2*)&hmR[r * 128 + c0] = make_float2(n0v, n1v);
        }
    }
    __syncthreads();

    // ---- GEMM2: acc2[r][c] = sum_k hm[r][k] * w1[k][c0+c] ----
    float acc2[8][2];
    #pragma unroll
    for (int r = 0; r < 8; ++r) { acc2[r][0] = 0.f; acc2[r][1] = 0.f; }
    #pragma unroll 2
    for (int k = 0; k < 128; ++k) {
        float2 w = *(const float2*)&w1[k * 128 + c0];
        float hr[8];
        #pragma unroll
        for (int r = 0; r < 8; ++r) hr[r] = hmR[r * 128 + k];
        #pragma unroll
        for (int r = 0; r < 8; ++r) {
            acc2[r][0] += hr[r] * w.x;
            acc2[r][1] += hr[r] * w.y;
        }
    }

    // ---- residual + LN2 + store ----
    {
        float2 bv = *(const float2*)&b1[c0];
        float2 gv = *(const float2*)&lng[c0];
        float2 tv = *(const float2*)&lnb[c0];
        float rs[8], rq[8];
        #pragma unroll
        for (int r = 0; r < 8; ++r) {
            float2 xv = *(const float2*)&x[(n0 + r) * 128 + c0];
            float v0 = acc2[r][0] + bv.x + xv.x;
            float v1 = acc2[r][1] + bv.y + xv.y;
            acc2[r][0] = v0; acc2[r][1] = v1;
            rs[r] = v0 + v1;
            rq[r] = v0 * v0 + v1 * v1;
        }
        #pragma unroll
        for (int m = 1; m <= 32; m <<= 1)
            #pragma unroll
            for (int r = 0; r < 8; ++r) {
                rs[r] += __shfl_xor(rs[r], m);
                rq[r] += __shfl_xor(rq[r], m);
            }
        #pragma unroll
        for (int r = 0; r < 8; ++r) {
            float mu  = rs[r] * (1.f / 128.f);
            float var = rq[r] * (1.f / 128.f) - mu * mu;
            float rv  = rsqrtf(var + 1e-5f);
            float o0 = (acc2[r][0] - mu) * rv * gv.x + tv.x;
            float o1 = (acc2[r][1] - mu) * rv * gv.y + tv.y;
            *(float2*)&out[(n0 + r) * 128 + c0] = make_float2(o0, o1);
        }
    }
}

extern "C" void kernel_launch(void* const* d_in, const int* in_sizes, int n_in,
                              void* d_out, int out_size, void* d_ws, size_t ws_size,
                              hipStream_t stream) {
    const float* x     = (const float*)d_in[0];
    const float* ea    = (const float*)d_in[1];
    const float* lpe   = (const float*)d_in[2];
    const float* rwse  = (const float*)d_in[3];
    const int*   ei    = (const int*)d_in[4];
    const int*   batch = (const int*)d_in[5];
    const float* We    = (const float*)d_in[6];
    const float* be    = (const float*)d_in[7];
    const float* Wx    = (const float*)d_in[8];
    const float* bx    = (const float*)d_in[9];
    const float* w0    = (const float*)d_in[10];
    const float* b0    = (const float*)d_in[11];
    const float* w1    = (const float*)d_in[12];
    const float* b1    = (const float*)d_in[13];
    const float* w2    = (const float*)d_in[14];
    const float* b2    = (const float*)d_in[15];
    const float* w3    = (const float*)d_in[16];
    const float* b3    = (const float*)d_in[17];
    const float* gWi   = (const float*)d_in[18];
    const float* gWh   = (const float*)d_in[19];
    const float* gbi   = (const float*)d_in[20];
    const float* gbh   = (const float*)d_in[21];
    const float* mWin  = (const float*)d_in[22];
    const float* mcw   = (const float*)d_in[23];
    const float* mcb   = (const float*)d_in[24];
    const float* mWx   = (const float*)d_in[25];
    const float* mWdt  = (const float*)d_in[26];
    const float* mbdt  = (const float*)d_in[27];
    const float* mAlog = (const float*)d_in[28];
    const float* mDp   = (const float*)d_in[29];
    const float* mWout = (const float*)d_in[30];
    const float* lnmg  = (const float*)d_in[31];
    const float* lnmb  = (const float*)d_in[32];
    const float* mgw0  = (const float*)d_in[33];
    const float* mgb0  = (const float*)d_in[34];
    const float* mgg0  = (const float*)d_in[35];
    const float* mgbt0 = (const float*)d_in[36];
    const float* mgw1  = (const float*)d_in[37];
    const float* mgb1  = (const float*)d_in[38];
    const float* lng   = (const float*)d_in[39];
    const float* lnb   = (const float*)d_in[40];
    float* out = (float*)d_out;

    float* ws     = (float*)d_ws;
    float* agg    = ws;                     // 3*N*128 = 18,874,368 floats
    float* P0     = agg + 18874368;         // N*160  =  7,864,320
    float* scores = P0 + 7864320;           // N
    float* hbuf   = scores + N_NODES;       // B*160
    float* hw0    = hbuf + 10240;           // B*160
    float* tokb   = hw0 + 10240;            // B*4*160
    float* mo     = tokb + 40960;           // B*160
    int*   cnt    = (int*)(mo + 10240);     // N ints (also cursor source)
    int*   off    = cnt + N_NODES;          // N+1 ints
    int*   cursor = off + N_NODES + 1;      // N ints
    int*   eids   = cursor + N_NODES;       // E ints

    hipMemsetAsync(cnt, 0, (size_t)N_NODES * 4, stream);
    hipMemsetAsync(hbuf, 0, (size_t)20480 * 4, stream);  // h and hw0

    const int* src = ei;
    const int* dstp = ei + NEDGE;

    k_hist<<<NEDGE / 256, 256, 0, stream>>>(dstp, cnt);
    k_scan<<<1, 256, 0, stream>>>(cnt, off, cursor);
    k_scatter<<<NEDGE / 256, 256, 0, stream>>>(dstp, cursor, eids);
    k_agg<<<N_NODES, 128, 0, stream>>>(x, ea, src, off, eids, We, be, agg);

    dim3 g3(N_NODES / 16, 3);
    k_xs<<<g3, 128, 0, stream>>>(x, agg, Wx, bx);
    k_p0<<<N_NODES / 16, 192, 0, stream>>>(x, lpe, rwse, w0, b0, P0);
    for (int t = 0; t < 4; ++t) {
        k_mlp<<<N_NODES / 16, 192, 0, stream>>>(P0, hw0, w1, b1, w2, b2, w3, b3, scores);
        k_graph<<<BGRAPH, 256, 0, stream>>>(scores, x, lpe, rwse, gWi, gWh, gbi, gbh,
                                            w0 + 160 * 160, hbuf, hw0, tokb, t);
    }
    k_mamba<<<BGRAPH, 256, 0, stream>>>(tokb, mWin, mcw, mcb, mWx, mWdt, mbdt,
                                        mAlog, mDp, mWout, lnmg, lnmb, mo);
    k_final<<<N_NODES / 8, 64, 0, stream>>>(x, agg, batch, mo, mgw0, mgb0, mgg0, mgbt0,
                                            mgw1, mgb1, lng, lnb, out);
}

// Round 5
// 1610.405 us; speedup vs baseline: 1.1783x; 1.1783x over previous
//
#include <hip/hip_runtime.h>
#include <math.h>

#define N_NODES 49152
#define BGRAPH  64
#define MAXN_   768
#define NEDGE   491520
#define DD      128
#define CC      160
#define DI_     320
#define DS_     128
#define DTR_    10

__device__ __forceinline__ float sigm(float x) { return 1.f / (1.f + __expf(-x)); }
__device__ __forceinline__ float softplusf(float x) {
    return (x > 20.f) ? x : log1pf(__expf(x));
}

// block-wide sum: all threads get result. blockDim multiple of 64.
__device__ __forceinline__ float blkSum(float v, float* scratch) {
    __syncthreads();
    #pragma unroll
    for (int off = 32; off > 0; off >>= 1) v += __shfl_down(v, off);
    if ((threadIdx.x & 63) == 0) scratch[threadIdx.x >> 6] = v;
    __syncthreads();
    int nw = blockDim.x >> 6;
    float s = 0.f;
    for (int i = 0; i < nw; ++i) s += scratch[i];
    return s;
}

__device__ __forceinline__ float blkMax(float v, float* scratch) {
    __syncthreads();
    #pragma unroll
    for (int off = 32; off > 0; off >>= 1) v = fmaxf(v, __shfl_down(v, off));
    if ((threadIdx.x & 63) == 0) scratch[threadIdx.x >> 6] = v;
    __syncthreads();
    int nw = blockDim.x >> 6;
    float s = scratch[0];
    for (int i = 1; i < nw; ++i) s = fmaxf(s, scratch[i]);
    return s;
}

// ---------------- CSR build: histogram / scan / scatter -----------------------
__global__ void k_hist(const int* __restrict__ dst, int* __restrict__ cnt) {
    int e = blockIdx.x * 256 + threadIdx.x;
    if (e < NEDGE) atomicAdd(&cnt[dst[e]], 1);
}

__global__ void k_scan(const int* __restrict__ cnt, int* __restrict__ off,
                       int* __restrict__ cursor) {
    __shared__ int part[256];
    const int t = threadIdx.x;           // 256 threads, 192 nodes each
    const int base = t * 192;
    int s = 0;
    for (int i = 0; i < 192; ++i) s += cnt[base + i];
    part[t] = s;
    __syncthreads();
    if (t == 0) {
        int run = 0;
        for (int i = 0; i < 256; ++i) { int v = part[i]; part[i] = run; run += v; }
    }
    __syncthreads();
    int run = part[t];
    for (int i = 0; i < 192; ++i) {
        int idx = base + i;
        off[idx] = run;
        cursor[idx] = run;
        run += cnt[idx];
    }
    if (t == 255) off[N_NODES] = run;    // == NEDGE
}

__global__ void k_scatter(const int* __restrict__ dst, int* __restrict__ cursor,
                          int* __restrict__ eids) {
    int e = blockIdx.x * 256 + threadIdx.x;
    if (e < NEDGE) {
        int pos = atomicAdd(&cursor[dst[e]], 1);
        eids[pos] = e;
    }
}

// ---------------- K2': gather-style gated aggregation (no atomics) ------------
__global__ void k_agg(const float* __restrict__ x, const float* __restrict__ ea,
                      const int* __restrict__ src,
                      const int* __restrict__ off, const int* __restrict__ eids,
                      const float* __restrict__ We, const float* __restrict__ be,
                      float* __restrict__ agg)
{
    const int n = blockIdx.x;
    const int d = threadIdx.x;   // 128
    const float w00 = We[d],           w01 = We[128 + d],       bb0 = be[d];
    const float w10 = We[256 + d],     w11 = We[256 + 128 + d], bb1 = be[128 + d];
    const float w20 = We[512 + d],     w21 = We[512 + 128 + d], bb2 = be[256 + d];
    const int beg = off[n], end = off[n + 1];
    float acc0 = 0.f, acc1 = 0.f, acc2 = 0.f;
    for (int i = beg; i < end; ++i) {
        int e = eids[i];
        int s = src[e];
        float ea0 = ea[2 * e], ea1 = ea[2 * e + 1];
        float xv = x[s * DD + d];
        acc0 += xv * sigm(ea0 * w00 + ea1 * w01 + bb0);
        acc1 += xv * sigm(ea0 * w10 + ea1 * w11 + bb1);
        acc2 += xv * sigm(ea0 * w20 + ea1 * w21 + bb2);
    }
    agg[              n * DD + d] = acc0;
    agg[N_NODES * DD + n * DD + d] = acc1;
    agg[2 * N_NODES * DD + n * DD + d] = acc2;
}

// ---------------- K3: xs_i = relu((x+agg_i)@Wx_i + bx_i), in-place over agg ----
__global__ void k_xs(const float* __restrict__ x, float* __restrict__ agg,
                     const float* __restrict__ Wx, const float* __restrict__ bx)
{
    const int i  = blockIdx.y;
    const int n0 = blockIdx.x * 16;
    const int j  = threadIdx.x;  // 128
    __shared__ float inL[16 * 128];
    float* aggi = agg + i * (N_NODES * DD);
    #pragma unroll
    for (int r = 0; r < 16; ++r)
        inL[r * 128 + j] = x[(n0 + r) * DD + j] + aggi[(n0 + r) * DD + j];
    __syncthreads();
    float acc[16];
    #pragma unroll
    for (int r = 0; r < 16; ++r) acc[r] = 0.f;
    const float* W = Wx + i * (DD * DD);
    for (int k = 0; k < 128; ++k) {
        float w = W[k * 128 + j];
        #pragma unroll
        for (int r = 0; r < 16; ++r) acc[r] += inL[r * 128 + k] * w;
    }
    float bb = bx[i * 128 + j];
    #pragma unroll
    for (int r = 0; r < 16; ++r) {
        float v = acc[r] + bb;
        aggi[(n0 + r) * DD + j] = v > 0.f ? v : 0.f;
    }
}

// ---------------- K4: P0 = xp @ wm_w0[:160] + b0  (step-invariant) ------------
__global__ void k_p0(const float* __restrict__ x, const float* __restrict__ lpe,
                     const float* __restrict__ rwse, const float* __restrict__ w0,
                     const float* __restrict__ b0, float* __restrict__ P0)
{
    const int n0 = blockIdx.x * 16;
    const int j  = threadIdx.x;  // 192
    __shared__ float inL[16 * 160];
    for (int idx = j; idx < 16 * 160; idx += 192) {
        int r = idx / 160, k = idx - r * 160;
        int n = n0 + r;
        float v;
        if (k < 128)      v = x[n * 128 + k];
        else if (k < 144) v = lpe[n * 16 + (k - 128)];
        else              v = rwse[n * 16 + (k - 144)];
        inL[idx] = v;
    }
    __syncthreads();
    if (j < 160) {
        float acc[16];
        #pragma unroll
        for (int r = 0; r < 16; ++r) acc[r] = 0.f;
        for (int k = 0; k < 160; ++k) {
            float w = w0[k * 160 + j];
            #pragma unroll
            for (int r = 0; r < 16; ++r) acc[r] += inL[r * 160 + k] * w;
        }
        float bb = b0[j];
        #pragma unroll
        for (int r = 0; r < 16; ++r) P0[(n0 + r) * 160 + j] = acc[r] + bb;
    }
}

// ---------------- K6: per-row MLP -> attention scores -------------------------
// One wave per 8 rows. Lane l owns padded cols {l, 64+l, 128+(l&31)} (3rd col
// valid only for l<32; duplicated loads for l>=32 are masked at use). 24 regs
// of accumulator -> no spill. A-operand broadcast from [k][r] LDS via
// ds_read_b128 x2. a3 stays in registers; score via 64-lane butterfly.
__global__ __launch_bounds__(64) void k_mlp(
        const float* __restrict__ P0, const float* __restrict__ hw0,
        const float* __restrict__ w1, const float* __restrict__ b1,
        const float* __restrict__ w2, const float* __restrict__ b2,
        const float* __restrict__ w3, const float* __restrict__ b3,
        float* __restrict__ scores)
{
    const int n0 = blockIdx.x * 8;
    const int b  = n0 / MAXN_;       // 8 | 768 -> uniform per block
    const int l  = threadIdx.x;      // 64
    const int c1 = l, c2 = 64 + l, c3 = 128 + (l & 31);
    const bool c3v = (l < 32);
    __shared__ float bufA[160 * 8];  // [k][r]
    __shared__ float bufB[160 * 8];

    // stage a1 = relu(P0 + hw0[b]) as [k][r]
    for (int idx = l; idx < 1280; idx += 64) {
        int r = idx & 7, k = idx >> 3;
        float v = P0[(n0 + r) * 160 + k] + hw0[b * 160 + k];
        bufA[idx] = v > 0.f ? v : 0.f;
    }
    __syncthreads();

    // ---- layer: a2 = relu(a1 @ w1 + b1) -> bufB ----
    {
        float a1[8], a2[8], a3[8];
        #pragma unroll
        for (int r = 0; r < 8; ++r) { a1[r] = 0.f; a2[r] = 0.f; a3[r] = 0.f; }
        #pragma unroll 4
        for (int k = 0; k < 160; ++k) {
            float4 f0 = *(const float4*)&bufA[k * 8];
            float4 f1 = *(const float4*)&bufA[k * 8 + 4];
            float wv1 = w1[k * 160 + c1];
            float wv2 = w1[k * 160 + c2];
            float wv3 = w1[k * 160 + c3];
            float ar[8] = {f0.x, f0.y, f0.z, f0.w, f1.x, f1.y, f1.z, f1.w};
            #pragma unroll
            for (int r = 0; r < 8; ++r) {
                a1[r] += ar[r] * wv1;
                a2[r] += ar[r] * wv2;
                a3[r] += ar[r] * wv3;
            }
        }
        float bb1 = b1[c1], bb2 = b1[c2], bb3 = b1[c3];
        #pragma unroll
        for (int r = 0; r < 8; ++r) {
            float v1 = a1[r] + bb1; v1 = v1 > 0.f ? v1 : 0.f;
            float v2 = a2[r] + bb2; v2 = v2 > 0.f ? v2 : 0.f;
            bufB[c1 * 8 + r] = v1;
            bufB[c2 * 8 + r] = v2;
            if (c3v) {
                float v3 = a3[r] + bb3; v3 = v3 > 0.f ? v3 : 0.f;
                bufB[c3 * 8 + r] = v3;
            }
        }
    }
    __syncthreads();

    // ---- layer: a3 = relu(a2 @ w2 + b2), fused score = a3 . w3 ----
    {
        float a1[8], a2[8], a3[8];
        #pragma unroll
        for (int r = 0; r < 8; ++r) { a1[r] = 0.f; a2[r] = 0.f; a3[r] = 0.f; }
        #pragma unroll 4
        for (int k = 0; k < 160; ++k) {
            float4 f0 = *(const float4*)&bufB[k * 8];
            float4 f1 = *(const float4*)&bufB[k * 8 + 4];
            float wv1 = w2[k * 160 + c1];
            float wv2 = w2[k * 160 + c2];
            float wv3 = w2[k * 160 + c3];
            float ar[8] = {f0.x, f0.y, f0.z, f0.w, f1.x, f1.y, f1.z, f1.w};
            #pragma unroll
            for (int r = 0; r < 8; ++r) {
                a1[r] += ar[r] * wv1;
                a2[r] += ar[r] * wv2;
                a3[r] += ar[r] * wv3;
            }
        }
        float bb1 = b2[c1], bb2 = b2[c2], bb3 = b2[c3];
        float w3v1 = w3[c1], w3v2 = w3[c2], w3v3 = w3[c3];
        float p[8];
        #pragma unroll
        for (int r = 0; r < 8; ++r) {
            float v1 = a1[r] + bb1; v1 = v1 > 0.f ? v1 : 0.f;
            float v2 = a2[r] + bb2; v2 = v2 > 0.f ? v2 : 0.f;
            float v3 = a3[r] + bb3; v3 = v3 > 0.f ? v3 : 0.f;
            if (!c3v) v3 = 0.f;   // lanes 32-63 duplicate cols 128-159: mask
            p[r] = v1 * w3v1 + v2 * w3v2 + v3 * w3v3;
        }
        #pragma unroll
        for (int m = 1; m <= 32; m <<= 1)
            #pragma unroll
            for (int r = 0; r < 8; ++r) p[r] += __shfl_xor(p[r], m);
        if (l == 0) {
            float bb = b3[0];
            #pragma unroll
            for (int r = 0; r < 8; ++r) scores[n0 + r] = p[r] + bb;
        }
    }
}

// ---------------- K7: per-graph softmax + t + GRU + hw0_next ------------------
__global__ void k_graph(const float* __restrict__ scores,
                        const float* __restrict__ x, const float* __restrict__ lpe,
                        const float* __restrict__ rwse,
                        const float* __restrict__ Wi, const float* __restrict__ Wh,
                        const float* __restrict__ bi, const float* __restrict__ bh,
                        const float* __restrict__ w0h,
                        float* __restrict__ h, float* __restrict__ hw0,
                        float* __restrict__ tok, int step)
{
    const int b   = blockIdx.x;
    const int tid = threadIdx.x;  // 256
    __shared__ float eL[MAXN_];
    __shared__ float tL[160];
    __shared__ float hL[160];
    __shared__ float hN[160];
    __shared__ float red[8];
    const float inv_sqrt_d = 0.08838834764831845f;  // 128^-0.5

    float m = -1e30f;
    for (int i = tid; i < MAXN_; i += 256) {
        float q = scores[b * MAXN_ + i] * inv_sqrt_d;
        eL[i] = q;
        m = fmaxf(m, q);
    }
    m = blkMax(m, red);
    float s = 0.f;
    for (int i = tid; i < MAXN_; i += 256) {
        float e = __expf(eL[i] - m);
        eL[i] = e;
        s += e;
    }
    if (tid < 160) hL[tid] = h[b * 160 + tid];
    float S = blkSum(s, red);
    float scale = 1.f / (S * (float)MAXN_);
    // t = sum_i alpha_i * xp_i / MAXN
    if (tid < 160) {
        const int c = tid;
        float acc = 0.f;
        for (int i = 0; i < MAXN_; ++i) {
            int n = b * MAXN_ + i;
            float v;
            if (c < 128)      v = x[n * 128 + c];
            else if (c < 144) v = lpe[n * 16 + (c - 128)];
            else              v = rwse[n * 16 + (c - 144)];
            acc += eL[i] * v;
        }
        float tv = acc * scale;
        tL[c] = tv;
        tok[b * 640 + step * 160 + c] = tv;
    }
    __syncthreads();
    // GRU
    if (tid < 160) {
        const int c = tid;
        float gr = bi[c], gz = bi[160 + c], gn = bi[320 + c];
        float hr = bh[c], hz = bh[160 + c], hn = bh[320 + c];
        for (int k = 0; k < 160; ++k) {
            float tv = tL[k], hv = hL[k];
            gr += tv * Wi[k * 480 + c];
            gz += tv * Wi[k * 480 + 160 + c];
            gn += tv * Wi[k * 480 + 320 + c];
            hr += hv * Wh[k * 480 + c];
            hz += hv * Wh[k * 480 + 160 + c];
            hn += hv * Wh[k * 480 + 320 + c];
        }
        float r = sigm(gr + hr);
        float z = sigm(gz + hz);
        float n = tanhf(gn + r * hn);
        float hnew = (1.f - z) * n + z * hL[c];
        hN[c] = hnew;
        h[b * 160 + c] = hnew;
    }
    __syncthreads();
    // hw0_next = h_new @ wm_w0[160:,:]
    if (tid < 160) {
        const int j = tid;
        float acc = 0.f;
        for (int k = 0; k < 160; ++k) acc += hN[k] * w0h[k * 160 + j];
        hw0[b * 160 + j] = acc;
    }
}

// ---------------- K9: mamba-ish part, one block per graph, t=3 output only ----
__global__ void k_mamba(const float* __restrict__ tok,
                        const float* __restrict__ Win, const float* __restrict__ convw,
                        const float* __restrict__ convb,
                        const float* __restrict__ Wx, const float* __restrict__ Wdt,
                        const float* __restrict__ bdt,
                        const float* __restrict__ Alog, const float* __restrict__ Dp,
                        const float* __restrict__ Wout,
                        const float* __restrict__ lng, const float* __restrict__ lnb,
                        float* __restrict__ mo_last)
{
    const int b   = blockIdx.x;
    const int tid = threadIdx.x;  // 256
    __shared__ float tokL[640];
    __shared__ float xpre[1280];
    __shared__ float xmL[1280];
    __shared__ float z3L[320];
    __shared__ float dtrL[40];
    __shared__ float BmL[512];
    __shared__ float Cm3L[128];
    __shared__ float dtL[1280];
    __shared__ float y3L[320];
    __shared__ float moL[160];
    __shared__ float red[8];

    for (int i = tid; i < 640; i += 256) tokL[i] = tok[b * 640 + i];
    __syncthreads();
    // xm_pre = tok @ Win[:, :320] ; z3 = tok[3] @ Win[:, 320:]
    for (int o = tid; o < 1280; o += 256) {
        int t = o / 320, d = o - t * 320;
        float acc = 0.f;
        for (int k = 0; k < 160; ++k) acc += tokL[t * 160 + k] * Win[k * 640 + d];
        xpre[o] = acc;
    }
    for (int d = tid; d < 320; d += 256) {
        float acc = 0.f;
        for (int k = 0; k < 160; ++k) acc += tokL[480 + k] * Win[k * 640 + 320 + d];
        z3L[d] = acc;
    }
    __syncthreads();
    // causal conv + silu
    for (int o = tid; o < 1280; o += 256) {
        int t = o / 320, d = o - t * 320;
        float acc = convb[d];
        #pragma unroll
        for (int k = 0; k < 4; ++k) {
            int tt = t + k - 3;
            if (tt >= 0) acc += xpre[tt * 320 + d] * convw[d * 4 + k];
        }
        xmL[o] = acc * sigm(acc);
    }
    __syncthreads();
    // dbl = xm @ Wx : dtr(4x10), Bm(4x128), Cm(t=3 only, 128)
    for (int o = tid; o < 680; o += 256) {
        int t, col;
        if (o < 40)       { t = o / 10; col = o - t * 10; }
        else if (o < 552) { int i = o - 40; t = i >> 7; col = 10 + (i & 127); }
        else              { t = 3; col = 138 + (o - 552); }
        float acc = 0.f;
        for (int k = 0; k < 320; ++k) acc += xmL[t * 320 + k] * Wx[k * 266 + col];
        if (o < 40)       dtrL[o] = acc;
        else if (o < 552) BmL[o - 40] = acc;
        else              Cm3L[o - 552] = acc;
    }
    __syncthreads();
    // dt = softplus(dtr @ Wdt + bdt)
    for (int o = tid; o < 1280; o += 256) {
        int t = o / 320, d = o - t * 320;
        float acc = bdt[d];
        #pragma unroll
        for (int r = 0; r < 10; ++r) acc += dtrL[t * 10 + r] * Wdt[r * 320 + d];
        dtL[o] = softplusf(acc);
    }
    __syncthreads();
    // scan over T=4, keep only y at t=3; wave w handles dim d, lane handles 2 states
    {
        int w = tid >> 6, lane = tid & 63;
        for (int dbase = 0; dbase < 320; dbase += 4) {
            int d = dbase + w;
            float A0 = -__expf(Alog[d * 128 + lane]);
            float A1 = -__expf(Alog[d * 128 + 64 + lane]);
            float s0 = 0.f, s1 = 0.f;
            #pragma unroll
            for (int t = 0; t < 4; ++t) {
                float dtv = dtL[t * 320 + d];
                float xv  = xmL[t * 320 + d];
                float c0  = dtv * xv;
                s0 = s0 * __expf(dtv * A0) + c0 * BmL[t * 128 + lane];
                s1 = s1 * __expf(dtv * A1) + c0 * BmL[t * 128 + 64 + lane];
            }
            float contrib = s0 * Cm3L[lane] + s1 * Cm3L[64 + lane];
            #pragma unroll
            for (int off = 32; off > 0; off >>= 1) contrib += __shfl_down(contrib, off);
            if (lane == 0) {
                float y  = contrib + Dp[d] * xmL[3 * 320 + d];
                float zz = z3L[d];
                y3L[d] = y * (zz * sigm(zz));
            }
        }
    }
    __syncthreads();
    // mo = LN(y3 @ Wout)
    if (tid < 160) {
        float acc = 0.f;
        for (int d = 0; d < 320; ++d) acc += y3L[d] * Wout[d * 160 + tid];
        moL[tid] = acc;
    }
    float v  = (tid < 160) ? moL[tid] : 0.f;   // moL write is own-thread; blkSum barriers cover others
    float sm = blkSum(v, red);
    float sq = blkSum(v * v, red);
    float mu  = sm / 160.f;
    float var = sq / 160.f - mu * mu;
    if (tid < 160)
        mo_last[b * 160 + tid] = (moL[tid] - mu) * rsqrtf(var + 1e-5f) * lng[tid] + lnb[tid];
}

// ---------------- K10 helpers: chunked staging for k_final --------------------
__device__ __forceinline__ void fin_load(float stg[17], int jj, int n0, int l,
                                         const float* __restrict__ xs,
                                         const float* __restrict__ mo_last,
                                         const int* __restrict__ batch) {
    int base = 136 * jj;
    #pragma unroll
    for (int t = 0; t < 17; ++t) {
        int idx = t * 64 + l;
        int r = idx & 7, k = base + (idx >> 3);
        stg[t] = (k < 384)
            ? xs[(k >> 7) * (N_NODES * 128) + (n0 + r) * 128 + (k & 127)]
            : mo_last[batch[n0 + r] * 160 + (k - 384)];
    }
}

// ---------------- K10: merge MLP + two LayerNorms -> out ----------------------
// One wave per 8-row tile; lane owns 2 cols (16 accs, no spill). catT staged in
// 4 chunks of 136 k (double-buffered 2x4.35 KB) -> LDS 12.8 KB (was 21.5 KB,
// which capped occupancy at 7 wg/CU). Loads for chunk j+1 issued before compute
// of chunk j (single-wave block: no barriers, compiler waitcnts only).
__global__ __launch_bounds__(64) void k_final(
        const float* __restrict__ x, const float* __restrict__ xs,
        const int* __restrict__ batch, const float* __restrict__ mo_last,
        const float* __restrict__ w0, const float* __restrict__ b0,
        const float* __restrict__ g0, const float* __restrict__ beta0,
        const float* __restrict__ w1, const float* __restrict__ b1,
        const float* __restrict__ lng, const float* __restrict__ lnb,
        float* __restrict__ out)
{
    const int n0 = blockIdx.x * 8;
    const int l  = threadIdx.x;      // 64
    const int c0 = l * 2;
    __shared__ float catC[2][136 * 8];  // [chunk][kk][r]
    __shared__ float hmR[8 * 128];      // [r][k]

    float stg[17];
    float acc[8][2];
    #pragma unroll
    for (int r = 0; r < 8; ++r) { acc[r][0] = 0.f; acc[r][1] = 0.f; }

    fin_load(stg, 0, n0, l, xs, mo_last, batch);
    #pragma unroll
    for (int t = 0; t < 17; ++t) catC[0][t * 64 + l] = stg[t];
    fin_load(stg, 1, n0, l, xs, mo_last, batch);
    __syncthreads();

    // ---- GEMM1 over 4 chunks ----
    for (int j = 0; j < 4; ++j) {
        const float* buf = catC[j & 1];
        const float* wp  = w0 + (size_t)(j * 136) * 128 + c0;
        #pragma unroll 4
        for (int kk = 0; kk < 136; ++kk) {
            float4 ca = *(const float4*)&buf[kk * 8];
            float4 cb = *(const float4*)&buf[kk * 8 + 4];
            float2 w  = *(const float2*)&wp[kk * 128];
            float cr[8] = {ca.x, ca.y, ca.z, ca.w, cb.x, cb.y, cb.z, cb.w};
            #pragma unroll
            for (int r = 0; r < 8; ++r) {
                acc[r][0] += cr[r] * w.x;
                acc[r][1] += cr[r] * w.y;
            }
        }
        if (j < 3) {
            #pragma unroll
            for (int t = 0; t < 17; ++t) catC[(j + 1) & 1][t * 64 + l] = stg[t];
            if (j < 2) fin_load(stg, j + 2, n0, l, xs, mo_last, batch);
        }
        __syncthreads();
    }

    // ---- LN1 + relu (per row over 128 cols), write hmR ----
    {
        float2 bv = *(const float2*)&b0[c0];
        float2 gv = *(const float2*)&g0[c0];
        float2 tv = *(const float2*)&beta0[c0];
        float rs[8], rq[8];
        #pragma unroll
        for (int r = 0; r < 8; ++r) {
            float v0 = acc[r][0] + bv.x;
            float v1 = acc[r][1] + bv.y;
            acc[r][0] = v0; acc[r][1] = v1;
            rs[r] = v0 + v1;
            rq[r] = v0 * v0 + v1 * v1;
        }
        #pragma unroll
        for (int m = 1; m <= 32; m <<= 1)
            #pragma unroll
            for (int r = 0; r < 8; ++r) {
                rs[r] += __shfl_xor(rs[r], m);
                rq[r] += __shfl_xor(rq[r], m);
            }
        #pragma unroll
        for (int r = 0; r < 8; ++r) {
            float mu  = rs[r] * (1.f / 128.f);
            float var = rq[r] * (1.f / 128.f) - mu * mu;
            float rv  = rsqrtf(var + 1e-5f);
            float n0v = (acc[r][0] - mu) * rv * gv.x + tv.x;
            float n1v = (acc[r][1] - mu) * rv * gv.y + tv.y;
            n0v = n0v > 0.f ? n0v : 0.f;
            n1v = n1v > 0.f ? n1v : 0.f;
            *(float2*)&hmR[r * 128 + c0] = make_float2(n0v, n1v);
        }
    }
    __syncthreads();

    // ---- GEMM2: acc2[r][c] = sum_k hm[r][k] * w1[k][c0+c] ----
    float acc2[8][2];
    #pragma unroll
    for (int r = 0; r < 8; ++r) { acc2[r][0] = 0.f; acc2[r][1] = 0.f; }
    #pragma unroll 2
    for (int k = 0; k < 128; ++k) {
        float2 w = *(const float2*)&w1[k * 128 + c0];
        float hr[8];
        #pragma unroll
        for (int r = 0; r < 8; ++r) hr[r] = hmR[r * 128 + k];
        #pragma unroll
        for (int r = 0; r < 8; ++r) {
            acc2[r][0] += hr[r] * w.x;
            acc2[r][1] += hr[r] * w.y;
        }
    }

    // ---- residual + LN2 + store ----
    {
        float2 bv = *(const float2*)&b1[c0];
        float2 gv = *(const float2*)&lng[c0];
        float2 tv = *(const float2*)&lnb[c0];
        float rs[8], rq[8];
        #pragma unroll
        for (int r = 0; r < 8; ++r) {
            float2 xv = *(const float2*)&x[(n0 + r) * 128 + c0];
            float v0 = acc2[r][0] + bv.x + xv.x;
            float v1 = acc2[r][1] + bv.y + xv.y;
            acc2[r][0] = v0; acc2[r][1] = v1;
            rs[r] = v0 + v1;
            rq[r] = v0 * v0 + v1 * v1;
        }
        #pragma unroll
        for (int m = 1; m <= 32; m <<= 1)
            #pragma unroll
            for (int r = 0; r < 8; ++r) {
                rs[r] += __shfl_xor(rs[r], m);
                rq[r] += __shfl_xor(rq[r], m);
            }
        #pragma unroll
        for (int r = 0; r < 8; ++r) {
            float mu  = rs[r] * (1.f / 128.f);
            float var = rq[r] * (1.f / 128.f) - mu * mu;
            float rv  = rsqrtf(var + 1e-5f);
            float o0 = (acc2[r][0] - mu) * rv * gv.x + tv.x;
            float o1 = (acc2[r][1] - mu) * rv * gv.y + tv.y;
            *(float2*)&out[(n0 + r) * 128 + c0] = make_float2(o0, o1);
        }
    }
}

extern "C" void kernel_launch(void* const* d_in, const int* in_sizes, int n_in,
                              void* d_out, int out_size, void* d_ws, size_t ws_size,
                              hipStream_t stream) {
    const float* x     = (const float*)d_in[0];
    const float* ea    = (const float*)d_in[1];
    const float* lpe   = (const float*)d_in[2];
    const float* rwse  = (const float*)d_in[3];
    const int*   ei    = (const int*)d_in[4];
    const int*   batch = (const int*)d_in[5];
    const float* We    = (const float*)d_in[6];
    const float* be    = (const float*)d_in[7];
    const float* Wx    = (const float*)d_in[8];
    const float* bx    = (const float*)d_in[9];
    const float* w0    = (const float*)d_in[10];
    const float* b0    = (const float*)d_in[11];
    const float* w1    = (const float*)d_in[12];
    const float* b1    = (const float*)d_in[13];
    const float* w2    = (const float*)d_in[14];
    const float* b2    = (const float*)d_in[15];
    const float* w3    = (const float*)d_in[16];
    const float* b3    = (const float*)d_in[17];
    const float* gWi   = (const float*)d_in[18];
    const float* gWh   = (const float*)d_in[19];
    const float* gbi   = (const float*)d_in[20];
    const float* gbh   = (const float*)d_in[21];
    const float* mWin  = (const float*)d_in[22];
    const float* mcw   = (const float*)d_in[23];
    const float* mcb   = (const float*)d_in[24];
    const float* mWx   = (const float*)d_in[25];
    const float* mWdt  = (const float*)d_in[26];
    const float* mbdt  = (const float*)d_in[27];
    const float* mAlog = (const float*)d_in[28];
    const float* mDp   = (const float*)d_in[29];
    const float* mWout = (const float*)d_in[30];
    const float* lnmg  = (const float*)d_in[31];
    const float* lnmb  = (const float*)d_in[32];
    const float* mgw0  = (const float*)d_in[33];
    const float* mgb0  = (const float*)d_in[34];
    const float* mgg0  = (const float*)d_in[35];
    const float* mgbt0 = (const float*)d_in[36];
    const float* mgw1  = (const float*)d_in[37];
    const float* mgb1  = (const float*)d_in[38];
    const float* lng   = (const float*)d_in[39];
    const float* lnb   = (const float*)d_in[40];
    float* out = (float*)d_out;

    float* ws     = (float*)d_ws;
    float* agg    = ws;                     // 3*N*128 = 18,874,368 floats
    float* P0     = agg + 18874368;         // N*160  =  7,864,320
    float* scores = P0 + 7864320;           // N
    float* hbuf   = scores + N_NODES;       // B*160
    float* hw0    = hbuf + 10240;           // B*160
    float* tokb   = hw0 + 10240;            // B*4*160
    float* mo     = tokb + 40960;           // B*160
    int*   cnt    = (int*)(mo + 10240);     // N ints (also cursor source)
    int*   off    = cnt + N_NODES;          // N+1 ints
    int*   cursor = off + N_NODES + 1;      // N ints
    int*   eids   = cursor + N_NODES;       // E ints

    hipMemsetAsync(cnt, 0, (size_t)N_NODES * 4, stream);
    hipMemsetAsync(hbuf, 0, (size_t)20480 * 4, stream);  // h and hw0

    const int* src = ei;
    const int* dstp = ei + NEDGE;

    k_hist<<<NEDGE / 256, 256, 0, stream>>>(dstp, cnt);
    k_scan<<<1, 256, 0, stream>>>(cnt, off, cursor);
    k_scatter<<<NEDGE / 256, 256, 0, stream>>>(dstp, cursor, eids);
    k_agg<<<N_NODES, 128, 0, stream>>>(x, ea, src, off, eids, We, be, agg);

    dim3 g3(N_NODES / 16, 3);
    k_xs<<<g3, 128, 0, stream>>>(x, agg, Wx, bx);
    k_p0<<<N_NODES / 16, 192, 0, stream>>>(x, lpe, rwse, w0, b0, P0);
    for (int t = 0; t < 4; ++t) {
        k_mlp<<<N_NODES / 8, 64, 0, stream>>>(P0, hw0, w1, b1, w2, b2, w3, b3, scores);
        k_graph<<<BGRAPH, 256, 0, stream>>>(scores, x, lpe, rwse, gWi, gWh, gbi, gbh,
                                            w0 + 160 * 160, hbuf, hw0, tokb, t);
    }
    k_mamba<<<BGRAPH, 256, 0, stream>>>(tokb, mWin, mcw, mcb, mWx, mWdt, mbdt,
                                        mAlog, mDp, mWout, lnmg, lnmb, mo);
    k_final<<<N_NODES / 8, 64, 0, stream>>>(x, agg, batch, mo, mgw0, mgb0, mgg0, mgbt0,
                                            mgw1, mgb1, lng, lnb, out);
}

// Round 6
// 1387.177 us; speedup vs baseline: 1.3680x; 1.1609x over previous
//
#include <hip/hip_runtime.h>
#include <math.h>

#define N_NODES 49152
#define BGRAPH  64
#define MAXN_   768
#define NEDGE   491520
#define DD      128
#define CC      160
#define DI_     320
#define DS_     128
#define DTR_    10

typedef __attribute__((ext_vector_type(8))) short bf16x8;
typedef __attribute__((ext_vector_type(4))) float f32x4;

__device__ __forceinline__ float sigm(float x) { return 1.f / (1.f + __expf(-x)); }
__device__ __forceinline__ float softplusf(float x) {
    return (x > 20.f) ? x : log1pf(__expf(x));
}
__device__ __forceinline__ unsigned short f2bf(float f) {   // RNE fp32->bf16
    unsigned int u = __float_as_uint(f);
    u += 0x7fffu + ((u >> 16) & 1u);
    return (unsigned short)(u >> 16);
}

// block-wide sum: all threads get result. blockDim multiple of 64.
__device__ __forceinline__ float blkSum(float v, float* scratch) {
    __syncthreads();
    #pragma unroll
    for (int off = 32; off > 0; off >>= 1) v += __shfl_down(v, off);
    if ((threadIdx.x & 63) == 0) scratch[threadIdx.x >> 6] = v;
    __syncthreads();
    int nw = blockDim.x >> 6;
    float s = 0.f;
    for (int i = 0; i < nw; ++i) s += scratch[i];
    return s;
}

__device__ __forceinline__ float blkMax(float v, float* scratch) {
    __syncthreads();
    #pragma unroll
    for (int off = 32; off > 0; off >>= 1) v = fmaxf(v, __shfl_down(v, off));
    if ((threadIdx.x & 63) == 0) scratch[threadIdx.x >> 6] = v;
    __syncthreads();
    int nw = blockDim.x >> 6;
    float s = scratch[0];
    for (int i = 1; i < nw; ++i) s = fmaxf(s, scratch[i]);
    return s;
}

// ---------------- CSR build: histogram / scan / scatter -----------------------
__global__ void k_hist(const int* __restrict__ dst, int* __restrict__ cnt) {
    int e = blockIdx.x * 256 + threadIdx.x;
    if (e < NEDGE) atomicAdd(&cnt[dst[e]], 1);
}

__global__ void k_scan(const int* __restrict__ cnt, int* __restrict__ off,
                       int* __restrict__ cursor) {
    __shared__ int part[256];
    const int t = threadIdx.x;           // 256 threads, 192 nodes each
    const int base = t * 192;
    int s = 0;
    for (int i = 0; i < 192; ++i) s += cnt[base + i];
    part[t] = s;
    __syncthreads();
    if (t == 0) {
        int run = 0;
        for (int i = 0; i < 256; ++i) { int v = part[i]; part[i] = run; run += v; }
    }
    __syncthreads();
    int run = part[t];
    for (int i = 0; i < 192; ++i) {
        int idx = base + i;
        off[idx] = run;
        cursor[idx] = run;
        run += cnt[idx];
    }
    if (t == 255) off[N_NODES] = run;    // == NEDGE
}

__global__ void k_scatter(const int* __restrict__ dst, int* __restrict__ cursor,
                          int* __restrict__ eids) {
    int e = blockIdx.x * 256 + threadIdx.x;
    if (e < NEDGE) {
        int pos = atomicAdd(&cursor[dst[e]], 1);
        eids[pos] = e;
    }
}

// ---------------- weight prep: w1,w2 -> bf16 transposed [col][k] (pad 168) ----
__global__ void k_cvt(const float* __restrict__ w1, const float* __restrict__ w2,
                      unsigned short* __restrict__ w1T, unsigned short* __restrict__ w2T)
{
    int id = blockIdx.x * 256 + threadIdx.x;
    if (id < 25600) {
        int c = id / 160, k = id - c * 160;
        w1T[c * 168 + k] = f2bf(w1[k * 160 + c]);
    } else if (id < 51200) {
        int i = id - 25600;
        int c = i / 160, k = i - c * 160;
        w2T[c * 168 + k] = f2bf(w2[k * 160 + c]);
    }
}

// ---------------- K2': gather-style gated aggregation (no atomics) ------------
__global__ void k_agg(const float* __restrict__ x, const float* __restrict__ ea,
                      const int* __restrict__ src,
                      const int* __restrict__ off, const int* __restrict__ eids,
                      const float* __restrict__ We, const float* __restrict__ be,
                      float* __restrict__ agg)
{
    const int n = blockIdx.x;
    const int d = threadIdx.x;   // 128
    const float w00 = We[d],           w01 = We[128 + d],       bb0 = be[d];
    const float w10 = We[256 + d],     w11 = We[256 + 128 + d], bb1 = be[128 + d];
    const float w20 = We[512 + d],     w21 = We[512 + 128 + d], bb2 = be[256 + d];
    const int beg = off[n], end = off[n + 1];
    float acc0 = 0.f, acc1 = 0.f, acc2 = 0.f;
    for (int i = beg; i < end; ++i) {
        int e = eids[i];
        int s = src[e];
        float ea0 = ea[2 * e], ea1 = ea[2 * e + 1];
        float xv = x[s * DD + d];
        acc0 += xv * sigm(ea0 * w00 + ea1 * w01 + bb0);
        acc1 += xv * sigm(ea0 * w10 + ea1 * w11 + bb1);
        acc2 += xv * sigm(ea0 * w20 + ea1 * w21 + bb2);
    }
    agg[              n * DD + d] = acc0;
    agg[N_NODES * DD + n * DD + d] = acc1;
    agg[2 * N_NODES * DD + n * DD + d] = acc2;
}

// ---------------- K3: xs_i = relu((x+agg_i)@Wx_i + bx_i), in-place over agg ----
__global__ void k_xs(const float* __restrict__ x, float* __restrict__ agg,
                     const float* __restrict__ Wx, const float* __restrict__ bx)
{
    const int i  = blockIdx.y;
    const int n0 = blockIdx.x * 16;
    const int j  = threadIdx.x;  // 128
    __shared__ float inL[16 * 128];
    float* aggi = agg + i * (N_NODES * DD);
    #pragma unroll
    for (int r = 0; r < 16; ++r)
        inL[r * 128 + j] = x[(n0 + r) * DD + j] + aggi[(n0 + r) * DD + j];
    __syncthreads();
    float acc[16];
    #pragma unroll
    for (int r = 0; r < 16; ++r) acc[r] = 0.f;
    const float* W = Wx + i * (DD * DD);
    for (int k = 0; k < 128; ++k) {
        float w = W[k * 128 + j];
        #pragma unroll
        for (int r = 0; r < 16; ++r) acc[r] += inL[r * 128 + k] * w;
    }
    float bb = bx[i * 128 + j];
    #pragma unroll
    for (int r = 0; r < 16; ++r) {
        float v = acc[r] + bb;
        aggi[(n0 + r) * DD + j] = v > 0.f ? v : 0.f;
    }
}

// ---------------- K4: P0 = xp @ wm_w0[:160] + b0  (step-invariant) ------------
__global__ void k_p0(const float* __restrict__ x, const float* __restrict__ lpe,
                     const float* __restrict__ rwse, const float* __restrict__ w0,
                     const float* __restrict__ b0, float* __restrict__ P0)
{
    const int n0 = blockIdx.x * 16;
    const int j  = threadIdx.x;  // 192
    __shared__ float inL[16 * 160];
    for (int idx = j; idx < 16 * 160; idx += 192) {
        int r = idx / 160, k = idx - r * 160;
        int n = n0 + r;
        float v;
        if (k < 128)      v = x[n * 128 + k];
        else if (k < 144) v = lpe[n * 16 + (k - 128)];
        else              v = rwse[n * 16 + (k - 144)];
        inL[idx] = v;
    }
    __syncthreads();
    if (j < 160) {
        float acc[16];
        #pragma unroll
        for (int r = 0; r < 16; ++r) acc[r] = 0.f;
        for (int k = 0; k < 160; ++k) {
            float w = w0[k * 160 + j];
            #pragma unroll
            for (int r = 0; r < 16; ++r) acc[r] += inL[r * 160 + k] * w;
        }
        float bb = b0[j];
        #pragma unroll
        for (int r = 0; r < 16; ++r) P0[(n0 + r) * 160 + j] = acc[r] + bb;
    }
}

// ---------------- K6: per-row MLP via bf16 MFMA -> attention scores -----------
// One wave per 16 rows. A (=activations) staged bf16 in LDS [m][k] pad 168
// (2-way banks only). B (=w1T/w2T, bf16 [col][k]) read straight from global
// (L2-resident, 54 KB). mfma_f32_16x16x32_bf16: A[m=lane&15][k=quad*8+j],
// B[k=quad*8+j][n=lane&15], C col=lane&15,row=quad*4+reg (m89/m91-verified).
// Layer-1 C-frags relu'd + cvt'd and written to A-layout LDS (m120 pattern).
// Score fused: p[reg] += relu(acc+b2)*w3[col], quad-local butterfly.
__global__ __launch_bounds__(64) void k_mlp(
        const float* __restrict__ P0, const float* __restrict__ hw0,
        const unsigned short* __restrict__ w1T, const float* __restrict__ b1,
        const unsigned short* __restrict__ w2T, const float* __restrict__ b2,
        const float* __restrict__ w3, const float* __restrict__ b3,
        float* __restrict__ scores)
{
    const int n0  = blockIdx.x * 16;
    const int b   = n0 / MAXN_;      // 16 | 768 -> uniform
    const int l   = threadIdx.x;     // 64
    const int col = l & 15, q = l >> 4;
    __shared__ unsigned short A1[16 * 168];
    __shared__ unsigned short A2[16 * 168];

    // stage a1 = relu(P0 + hw0[b]) as bf16 [m][k]
    for (int idx = l; idx < 2560; idx += 64) {
        int m = idx / 160, k = idx - m * 160;
        float v = P0[(n0 + m) * 160 + k] + hw0[b * 160 + k];
        A1[m * 168 + k] = f2bf(v > 0.f ? v : 0.f);
    }
    __syncthreads();

    // ---- layer 1: a2 = relu(a1 @ w1 + b1) -> A2 ----
    for (int tile = 0; tile < 10; ++tile) {
        int c0 = tile * 16;
        f32x4 acc = {0.f, 0.f, 0.f, 0.f};
        #pragma unroll
        for (int ks = 0; ks < 5; ++ks) {
            bf16x8 af = *(const bf16x8*)&A1[col * 168 + ks * 32 + q * 8];
            bf16x8 bf = *(const bf16x8*)&w1T[(c0 + col) * 168 + ks * 32 + q * 8];
            acc = __builtin_amdgcn_mfma_f32_16x16x32_bf16(af, bf, acc, 0, 0, 0);
        }
        float bb = b1[c0 + col];
        #pragma unroll
        for (int r = 0; r < 4; ++r) {
            float v = acc[r] + bb;
            A2[(q * 4 + r) * 168 + c0 + col] = f2bf(v > 0.f ? v : 0.f);
        }
    }
    __syncthreads();

    // ---- layer 2 + fused score ----
    float p[4] = {0.f, 0.f, 0.f, 0.f};
    for (int tile = 0; tile < 10; ++tile) {
        int c0 = tile * 16;
        f32x4 acc = {0.f, 0.f, 0.f, 0.f};
        #pragma unroll
        for (int ks = 0; ks < 5; ++ks) {
            bf16x8 af = *(const bf16x8*)&A2[col * 168 + ks * 32 + q * 8];
            bf16x8 bf = *(const bf16x8*)&w2T[(c0 + col) * 168 + ks * 32 + q * 8];
            acc = __builtin_amdgcn_mfma_f32_16x16x32_bf16(af, bf, acc, 0, 0, 0);
        }
        float bb = b2[c0 + col];
        float wv = w3[c0 + col];
        #pragma unroll
        for (int r = 0; r < 4; ++r) {
            float v = acc[r] + bb;
            v = v > 0.f ? v : 0.f;
            p[r] += v * wv;
        }
    }
    #pragma unroll
    for (int m = 1; m <= 8; m <<= 1)
        #pragma unroll
        for (int r = 0; r < 4; ++r) p[r] += __shfl_xor(p[r], m);
    if (col == 0) {
        float bb = b3[0];
        #pragma unroll
        for (int r = 0; r < 4; ++r) scores[n0 + q * 4 + r] = p[r] + bb;
    }
}

// ---------------- K7: per-graph softmax + t + GRU + hw0_next ------------------
__global__ void k_graph(const float* __restrict__ scores,
                        const float* __restrict__ x, const float* __restrict__ lpe,
                        const float* __restrict__ rwse,
                        const float* __restrict__ Wi, const float* __restrict__ Wh,
                        const float* __restrict__ bi, const float* __restrict__ bh,
                        const float* __restrict__ w0h,
                        float* __restrict__ h, float* __restrict__ hw0,
                        float* __restrict__ tok, int step)
{
    const int b   = blockIdx.x;
    const int tid = threadIdx.x;  // 256
    __shared__ float eL[MAXN_];
    __shared__ float tL[160];
    __shared__ float hL[160];
    __shared__ float hN[160];
    __shared__ float red[8];
    const float inv_sqrt_d = 0.08838834764831845f;  // 128^-0.5

    float m = -1e30f;
    for (int i = tid; i < MAXN_; i += 256) {
        float q = scores[b * MAXN_ + i] * inv_sqrt_d;
        eL[i] = q;
        m = fmaxf(m, q);
    }
    m = blkMax(m, red);
    float s = 0.f;
    for (int i = tid; i < MAXN_; i += 256) {
        float e = __expf(eL[i] - m);
        eL[i] = e;
        s += e;
    }
    if (tid < 160) hL[tid] = h[b * 160 + tid];
    float S = blkSum(s, red);
    float scale = 1.f / (S * (float)MAXN_);
    // t = sum_i alpha_i * xp_i / MAXN
    if (tid < 160) {
        const int c = tid;
        float acc = 0.f;
        for (int i = 0; i < MAXN_; ++i) {
            int n = b * MAXN_ + i;
            float v;
            if (c < 128)      v = x[n * 128 + c];
            else if (c < 144) v = lpe[n * 16 + (c - 128)];
            else              v = rwse[n * 16 + (c - 144)];
            acc += eL[i] * v;
        }
        float tv = acc * scale;
        tL[c] = tv;
        tok[b * 640 + step * 160 + c] = tv;
    }
    __syncthreads();
    // GRU
    if (tid < 160) {
        const int c = tid;
        float gr = bi[c], gz = bi[160 + c], gn = bi[320 + c];
        float hr = bh[c], hz = bh[160 + c], hn = bh[320 + c];
        for (int k = 0; k < 160; ++k) {
            float tv = tL[k], hv = hL[k];
            gr += tv * Wi[k * 480 + c];
            gz += tv * Wi[k * 480 + 160 + c];
            gn += tv * Wi[k * 480 + 320 + c];
            hr += hv * Wh[k * 480 + c];
            hz += hv * Wh[k * 480 + 160 + c];
            hn += hv * Wh[k * 480 + 320 + c];
        }
        float r = sigm(gr + hr);
        float z = sigm(gz + hz);
        float n = tanhf(gn + r * hn);
        float hnew = (1.f - z) * n + z * hL[c];
        hN[c] = hnew;
        h[b * 160 + c] = hnew;
    }
    __syncthreads();
    // hw0_next = h_new @ wm_w0[160:,:]
    if (tid < 160) {
        const int j = tid;
        float acc = 0.f;
        for (int k = 0; k < 160; ++k) acc += hN[k] * w0h[k * 160 + j];
        hw0[b * 160 + j] = acc;
    }
}

// ---------------- K9: mamba-ish part, one block per graph, t=3 output only ----
__global__ void k_mamba(const float* __restrict__ tok,
                        const float* __restrict__ Win, const float* __restrict__ convw,
                        const float* __restrict__ convb,
                        const float* __restrict__ Wx, const float* __restrict__ Wdt,
                        const float* __restrict__ bdt,
                        const float* __restrict__ Alog, const float* __restrict__ Dp,
                        const float* __restrict__ Wout,
                        const float* __restrict__ lng, const float* __restrict__ lnb,
                        float* __restrict__ mo_last)
{
    const int b   = blockIdx.x;
    const int tid = threadIdx.x;  // 256
    __shared__ float tokL[640];
    __shared__ float xpre[1280];
    __shared__ float xmL[1280];
    __shared__ float z3L[320];
    __shared__ float dtrL[40];
    __shared__ float BmL[512];
    __shared__ float Cm3L[128];
    __shared__ float dtL[1280];
    __shared__ float y3L[320];
    __shared__ float moL[160];
    __shared__ float red[8];

    for (int i = tid; i < 640; i += 256) tokL[i] = tok[b * 640 + i];
    __syncthreads();
    // xm_pre = tok @ Win[:, :320] ; z3 = tok[3] @ Win[:, 320:]
    for (int o = tid; o < 1280; o += 256) {
        int t = o / 320, d = o - t * 320;
        float acc = 0.f;
        for (int k = 0; k < 160; ++k) acc += tokL[t * 160 + k] * Win[k * 640 + d];
        xpre[o] = acc;
    }
    for (int d = tid; d < 320; d += 256) {
        float acc = 0.f;
        for (int k = 0; k < 160; ++k) acc += tokL[480 + k] * Win[k * 640 + 320 + d];
        z3L[d] = acc;
    }
    __syncthreads();
    // causal conv + silu
    for (int o = tid; o < 1280; o += 256) {
        int t = o / 320, d = o - t * 320;
        float acc = convb[d];
        #pragma unroll
        for (int k = 0; k < 4; ++k) {
            int tt = t + k - 3;
            if (tt >= 0) acc += xpre[tt * 320 + d] * convw[d * 4 + k];
        }
        xmL[o] = acc * sigm(acc);
    }
    __syncthreads();
    // dbl = xm @ Wx : dtr(4x10), Bm(4x128), Cm(t=3 only, 128)
    for (int o = tid; o < 680; o += 256) {
        int t, col;
        if (o < 40)       { t = o / 10; col = o - t * 10; }
        else if (o < 552) { int i = o - 40; t = i >> 7; col = 10 + (i & 127); }
        else              { t = 3; col = 138 + (o - 552); }
        float acc = 0.f;
        for (int k = 0; k < 320; ++k) acc += xmL[t * 320 + k] * Wx[k * 266 + col];
        if (o < 40)       dtrL[o] = acc;
        else if (o < 552) BmL[o - 40] = acc;
        else              Cm3L[o - 552] = acc;
    }
    __syncthreads();
    // dt = softplus(dtr @ Wdt + bdt)
    for (int o = tid; o < 1280; o += 256) {
        int t = o / 320, d = o - t * 320;
        float acc = bdt[d];
        #pragma unroll
        for (int r = 0; r < 10; ++r) acc += dtrL[t * 10 + r] * Wdt[r * 320 + d];
        dtL[o] = softplusf(acc);
    }
    __syncthreads();
    // scan over T=4, keep only y at t=3; wave w handles dim d, lane handles 2 states
    {
        int w = tid >> 6, lane = tid & 63;
        for (int dbase = 0; dbase < 320; dbase += 4) {
            int d = dbase + w;
            float A0 = -__expf(Alog[d * 128 + lane]);
            float A1 = -__expf(Alog[d * 128 + 64 + lane]);
            float s0 = 0.f, s1 = 0.f;
            #pragma unroll
            for (int t = 0; t < 4; ++t) {
                float dtv = dtL[t * 320 + d];
                float xv  = xmL[t * 320 + d];
                float c0  = dtv * xv;
                s0 = s0 * __expf(dtv * A0) + c0 * BmL[t * 128 + lane];
                s1 = s1 * __expf(dtv * A1) + c0 * BmL[t * 128 + 64 + lane];
            }
            float contrib = s0 * Cm3L[lane] + s1 * Cm3L[64 + lane];
            #pragma unroll
            for (int off = 32; off > 0; off >>= 1) contrib += __shfl_down(contrib, off);
            if (lane == 0) {
                float y  = contrib + Dp[d] * xmL[3 * 320 + d];
                float zz = z3L[d];
                y3L[d] = y * (zz * sigm(zz));
            }
        }
    }
    __syncthreads();
    // mo = LN(y3 @ Wout)
    if (tid < 160) {
        float acc = 0.f;
        for (int d = 0; d < 320; ++d) acc += y3L[d] * Wout[d * 160 + tid];
        moL[tid] = acc;
    }
    float v  = (tid < 160) ? moL[tid] : 0.f;   // moL write is own-thread; blkSum barriers cover others
    float sm = blkSum(v, red);
    float sq = blkSum(v * v, red);
    float mu  = sm / 160.f;
    float var = sq / 160.f - mu * mu;
    if (tid < 160)
        mo_last[b * 160 + tid] = (moL[tid] - mu) * rsqrtf(var + 1e-5f) * lng[tid] + lnb[tid];
}

// ---------------- K10 helpers: chunked staging for k_final --------------------
__device__ __forceinline__ void fin_load(float stg[17], int jj, int n0, int l,
                                         const float* __restrict__ xs,
                                         const float* __restrict__ mo_last,
                                         const int* __restrict__ batch) {
    int base = 136 * jj;
    #pragma unroll
    for (int t = 0; t < 17; ++t) {
        int idx = t * 64 + l;
        int r = idx & 7, k = base + (idx >> 3);
        stg[t] = (k < 384)
            ? xs[(k >> 7) * (N_NODES * 128) + (n0 + r) * 128 + (k & 127)]
            : mo_last[batch[n0 + r] * 160 + (k - 384)];
    }
}

// ---------------- K10: merge MLP + two LayerNorms -> out ----------------------
__global__ __launch_bounds__(64) void k_final(
        const float* __restrict__ x, const float* __restrict__ xs,
        const int* __restrict__ batch, const float* __restrict__ mo_last,
        const float* __restrict__ w0, const float* __restrict__ b0,
        const float* __restrict__ g0, const float* __restrict__ beta0,
        const float* __restrict__ w1, const float* __restrict__ b1,
        const float* __restrict__ lng, const float* __restrict__ lnb,
        float* __restrict__ out)
{
    const int n0 = blockIdx.x * 8;
    const int l  = threadIdx.x;      // 64
    const int c0 = l * 2;
    __shared__ float catC[2][136 * 8];  // [chunk][kk][r]
    __shared__ float hmR[8 * 128];      // [r][k]

    float stg[17];
    float acc[8][2];
    #pragma unroll
    for (int r = 0; r < 8; ++r) { acc[r][0] = 0.f; acc[r][1] = 0.f; }

    fin_load(stg, 0, n0, l, xs, mo_last, batch);
    #pragma unroll
    for (int t = 0; t < 17; ++t) catC[0][t * 64 + l] = stg[t];
    fin_load(stg, 1, n0, l, xs, mo_last, batch);
    __syncthreads();

    // ---- GEMM1 over 4 chunks ----
    for (int j = 0; j < 4; ++j) {
        const float* buf = catC[j & 1];
        const float* wp  = w0 + (size_t)(j * 136) * 128 + c0;
        #pragma unroll 4
        for (int kk = 0; kk < 136; ++kk) {
            float4 ca = *(const float4*)&buf[kk * 8];
            float4 cb = *(const float4*)&buf[kk * 8 + 4];
            float2 w  = *(const float2*)&wp[kk * 128];
            float cr[8] = {ca.x, ca.y, ca.z, ca.w, cb.x, cb.y, cb.z, cb.w};
            #pragma unroll
            for (int r = 0; r < 8; ++r) {
                acc[r][0] += cr[r] * w.x;
                acc[r][1] += cr[r] * w.y;
            }
        }
        if (j < 3) {
            #pragma unroll
            for (int t = 0; t < 17; ++t) catC[(j + 1) & 1][t * 64 + l] = stg[t];
            if (j < 2) fin_load(stg, j + 2, n0, l, xs, mo_last, batch);
        }
        __syncthreads();
    }

    // ---- LN1 + relu (per row over 128 cols), write hmR ----
    {
        float2 bv = *(const float2*)&b0[c0];
        float2 gv = *(const float2*)&g0[c0];
        float2 tv = *(const float2*)&beta0[c0];
        float rs[8], rq[8];
        #pragma unroll
        for (int r = 0; r < 8; ++r) {
            float v0 = acc[r][0] + bv.x;
            float v1 = acc[r][1] + bv.y;
            acc[r][0] = v0; acc[r][1] = v1;
            rs[r] = v0 + v1;
            rq[r] = v0 * v0 + v1 * v1;
        }
        #pragma unroll
        for (int m = 1; m <= 32; m <<= 1)
            #pragma unroll
            for (int r = 0; r < 8; ++r) {
                rs[r] += __shfl_xor(rs[r], m);
                rq[r] += __shfl_xor(rq[r], m);
            }
        #pragma unroll
        for (int r = 0; r < 8; ++r) {
            float mu  = rs[r] * (1.f / 128.f);
            float var = rq[r] * (1.f / 128.f) - mu * mu;
            float rv  = rsqrtf(var + 1e-5f);
            float n0v = (acc[r][0] - mu) * rv * gv.x + tv.x;
            float n1v = (acc[r][1] - mu) * rv * gv.y + tv.y;
            n0v = n0v > 0.f ? n0v : 0.f;
            n1v = n1v > 0.f ? n1v : 0.f;
            *(float2*)&hmR[r * 128 + c0] = make_float2(n0v, n1v);
        }
    }
    __syncthreads();

    // ---- GEMM2: acc2[r][c] = sum_k hm[r][k] * w1[k][c0+c] ----
    float acc2[8][2];
    #pragma unroll
    for (int r = 0; r < 8; ++r) { acc2[r][0] = 0.f; acc2[r][1] = 0.f; }
    #pragma unroll 2
    for (int k = 0; k < 128; ++k) {
        float2 w = *(const float2*)&w1[k * 128 + c0];
        float hr[8];
        #pragma unroll
        for (int r = 0; r < 8; ++r) hr[r] = hmR[r * 128 + k];
        #pragma unroll
        for (int r = 0; r < 8; ++r) {
            acc2[r][0] += hr[r] * w.x;
            acc2[r][1] += hr[r] * w.y;
        }
    }

    // ---- residual + LN2 + store ----
    {
        float2 bv = *(const float2*)&b1[c0];
        float2 gv = *(const float2*)&lng[c0];
        float2 tv = *(const float2*)&lnb[c0];
        float rs[8], rq[8];
        #pragma unroll
        for (int r = 0; r < 8; ++r) {
            float2 xv = *(const float2*)&x[(n0 + r) * 128 + c0];
            float v0 = acc2[r][0] + bv.x + xv.x;
            float v1 = acc2[r][1] + bv.y + xv.y;
            acc2[r][0] = v0; acc2[r][1] = v1;
            rs[r] = v0 + v1;
            rq[r] = v0 * v0 + v1 * v1;
        }
        #pragma unroll
        for (int m = 1; m <= 32; m <<= 1)
            #pragma unroll
            for (int r = 0; r < 8; ++r) {
                rs[r] += __shfl_xor(rs[r], m);
                rq[r] += __shfl_xor(rq[r], m);
            }
        #pragma unroll
        for (int r = 0; r < 8; ++r) {
            float mu  = rs[r] * (1.f / 128.f);
            float var = rq[r] * (1.f / 128.f) - mu * mu;
            float rv  = rsqrtf(var + 1e-5f);
            float o0 = (acc2[r][0] - mu) * rv * gv.x + tv.x;
            float o1 = (acc2[r][1] - mu) * rv * gv.y + tv.y;
            *(float2*)&out[(n0 + r) * 128 + c0] = make_float2(o0, o1);
        }
    }
}

extern "C" void kernel_launch(void* const* d_in, const int* in_sizes, int n_in,
                              void* d_out, int out_size, void* d_ws, size_t ws_size,
                              hipStream_t stream) {
    const float* x     = (const float*)d_in[0];
    const float* ea    = (const float*)d_in[1];
    const float* lpe   = (const float*)d_in[2];
    const float* rwse  = (const float*)d_in[3];
    const int*   ei    = (const int*)d_in[4];
    const int*   batch = (const int*)d_in[5];
    const float* We    = (const float*)d_in[6];
    const float* be    = (const float*)d_in[7];
    const float* Wx    = (const float*)d_in[8];
    const float* bx    = (const float*)d_in[9];
    const float* w0    = (const float*)d_in[10];
    const float* b0    = (const float*)d_in[11];
    const float* w1    = (const float*)d_in[12];
    const float* b1    = (const float*)d_in[13];
    const float* w2    = (const float*)d_in[14];
    const float* b2    = (const float*)d_in[15];
    const float* w3    = (const float*)d_in[16];
    const float* b3    = (const float*)d_in[17];
    const float* gWi   = (const float*)d_in[18];
    const float* gWh   = (const float*)d_in[19];
    const float* gbi   = (const float*)d_in[20];
    const float* gbh   = (const float*)d_in[21];
    const float* mWin  = (const float*)d_in[22];
    const float* mcw   = (const float*)d_in[23];
    const float* mcb   = (const float*)d_in[24];
    const float* mWx   = (const float*)d_in[25];
    const float* mWdt  = (const float*)d_in[26];
    const float* mbdt  = (const float*)d_in[27];
    const float* mAlog = (const float*)d_in[28];
    const float* mDp   = (const float*)d_in[29];
    const float* mWout = (const float*)d_in[30];
    const float* lnmg  = (const float*)d_in[31];
    const float* lnmb  = (const float*)d_in[32];
    const float* mgw0  = (const float*)d_in[33];
    const float* mgb0  = (const float*)d_in[34];
    const float* mgg0  = (const float*)d_in[35];
    const float* mgbt0 = (const float*)d_in[36];
    const float* mgw1  = (const float*)d_in[37];
    const float* mgb1  = (const float*)d_in[38];
    const float* lng   = (const float*)d_in[39];
    const float* lnb   = (const float*)d_in[40];
    float* out = (float*)d_out;

    float* ws     = (float*)d_ws;
    float* agg    = ws;                     // 3*N*128 = 18,874,368 floats
    float* P0     = agg + 18874368;         // N*160  =  7,864,320
    float* scores = P0 + 7864320;           // N
    float* hbuf   = scores + N_NODES;       // B*160
    float* hw0    = hbuf + 10240;           // B*160
    float* tokb   = hw0 + 10240;            // B*4*160
    float* mo     = tokb + 40960;           // B*160
    int*   cnt    = (int*)(mo + 10240);     // N ints (also cursor source)
    int*   off    = cnt + N_NODES;          // N+1 ints
    int*   cursor = off + N_NODES + 1;      // N ints
    int*   eids   = cursor + N_NODES;       // E ints
    uintptr_t pb  = ((uintptr_t)(eids + NEDGE) + 15) & ~(uintptr_t)15;
    unsigned short* w1T = (unsigned short*)pb;     // 160*168 bf16
    unsigned short* w2T = w1T + 160 * 168;         // 160*168 bf16

    hipMemsetAsync(cnt, 0, (size_t)N_NODES * 4, stream);
    hipMemsetAsync(hbuf, 0, (size_t)20480 * 4, stream);  // h and hw0

    const int* src = ei;
    const int* dstp = ei + NEDGE;

    k_hist<<<NEDGE / 256, 256, 0, stream>>>(dstp, cnt);
    k_scan<<<1, 256, 0, stream>>>(cnt, off, cursor);
    k_scatter<<<NEDGE / 256, 256, 0, stream>>>(dstp, cursor, eids);
    k_cvt<<<200, 256, 0, stream>>>(w1, w2, w1T, w2T);
    k_agg<<<N_NODES, 128, 0, stream>>>(x, ea, src, off, eids, We, be, agg);

    dim3 g3(N_NODES / 16, 3);
    k_xs<<<g3, 128, 0, stream>>>(x, agg, Wx, bx);
    k_p0<<<N_NODES / 16, 192, 0, stream>>>(x, lpe, rwse, w0, b0, P0);
    for (int t = 0; t < 4; ++t) {
        k_mlp<<<N_NODES / 16, 64, 0, stream>>>(P0, hw0, w1T, b1, w2T, b2, w3, b3, scores);
        k_graph<<<BGRAPH, 256, 0, stream>>>(scores, x, lpe, rwse, gWi, gWh, gbi, gbh,
                                            w0 + 160 * 160, hbuf, hw0, tokb, t);
    }
    k_mamba<<<BGRAPH, 256, 0, stream>>>(tokb, mWin, mcw, mcb, mWx, mWdt, mbdt,
                                        mAlog, mDp, mWout, lnmg, lnmb, mo);
    k_final<<<N_NODES / 8, 64, 0, stream>>>(x, agg, batch, mo, mgw0, mgb0, mgg0, mgbt0,
                                            mgw1, mgb1, lng, lnb, out);
}

// Round 9
// 1162.924 us; speedup vs baseline: 1.6317x; 1.1928x over previous
//
#include <hip/hip_runtime.h>
#include <math.h>

#define N_NODES 49152
#define BGRAPH  64
#define MAXN_   768
#define NEDGE   491520
#define DD      128
#define CC      160
#define DI_     320
#define DS_     128
#define DTR_    10

typedef __attribute__((ext_vector_type(8))) short bf16x8;
typedef __attribute__((ext_vector_type(4))) float f32x4;

__device__ __forceinline__ float sigm(float x) { return 1.f / (1.f + __expf(-x)); }
__device__ __forceinline__ float softplusf(float x) {
    return (x > 20.f) ? x : log1pf(__expf(x));
}
__device__ __forceinline__ unsigned short f2bf(float f) {   // RNE fp32->bf16
    unsigned int u = __float_as_uint(f);
    u += 0x7fffu + ((u >> 16) & 1u);
    return (unsigned short)(u >> 16);
}

// block-wide sum: all threads get result. blockDim multiple of 64.
__device__ __forceinline__ float blkSum(float v, float* scratch) {
    __syncthreads();
    #pragma unroll
    for (int off = 32; off > 0; off >>= 1) v += __shfl_down(v, off);
    if ((threadIdx.x & 63) == 0) scratch[threadIdx.x >> 6] = v;
    __syncthreads();
    int nw = blockDim.x >> 6;
    float s = 0.f;
    for (int i = 0; i < nw; ++i) s += scratch[i];
    return s;
}

__device__ __forceinline__ float blkMax(float v, float* scratch) {
    __syncthreads();
    #pragma unroll
    for (int off = 32; off > 0; off >>= 1) v = fmaxf(v, __shfl_down(v, off));
    if ((threadIdx.x & 63) == 0) scratch[threadIdx.x >> 6] = v;
    __syncthreads();
    int nw = blockDim.x >> 6;
    float s = scratch[0];
    for (int i = 1; i < nw; ++i) s = fmaxf(s, scratch[i]);
    return s;
}

// ---------------- CSR build: histogram / scan / scatter -----------------------
__global__ void k_hist(const int* __restrict__ dst, int* __restrict__ cnt) {
    int e = blockIdx.x * 256 + threadIdx.x;
    if (e < NEDGE) atomicAdd(&cnt[dst[e]], 1);
}

__global__ void k_scan(const int* __restrict__ cnt, int* __restrict__ off,
                       int* __restrict__ cursor) {
    __shared__ int part[256];
    const int t = threadIdx.x;           // 256 threads, 192 nodes each
    const int base = t * 192;
    int s = 0;
    for (int i = 0; i < 192; ++i) s += cnt[base + i];
    part[t] = s;
    __syncthreads();
    if (t == 0) {
        int run = 0;
        for (int i = 0; i < 256; ++i) { int v = part[i]; part[i] = run; run += v; }
    }
    __syncthreads();
    int run = part[t];
    for (int i = 0; i < 192; ++i) {
        int idx = base + i;
        off[idx] = run;
        cursor[idx] = run;
        run += cnt[idx];
    }
    if (t == 255) off[N_NODES] = run;    // == NEDGE
}

__global__ void k_scatter(const int* __restrict__ dst, int* __restrict__ cursor,
                          int* __restrict__ eids) {
    int e = blockIdx.x * 256 + threadIdx.x;
    if (e < NEDGE) {
        int pos = atomicAdd(&cursor[dst[e]], 1);
        eids[pos] = e;
    }
}

// ---------------- weight prep: w1,w2 -> bf16 transposed [col][k] (pad 168) ----
__global__ void k_cvt(const float* __restrict__ w1, const float* __restrict__ w2,
                      unsigned short* __restrict__ w1T, unsigned short* __restrict__ w2T)
{
    int id = blockIdx.x * 256 + threadIdx.x;
    if (id < 25600) {
        int c = id / 160, k = id - c * 160;
        w1T[c * 168 + k] = f2bf(w1[k * 160 + c]);
    } else if (id < 51200) {
        int i = id - 25600;
        int c = i / 160, k = i - c * 160;
        w2T[c * 168 + k] = f2bf(w2[k * 160 + c]);
    }
}

// ---------------- K2': gather-style gated aggregation (no atomics) ------------
__global__ void k_agg(const float* __restrict__ x, const float* __restrict__ ea,
                      const int* __restrict__ src,
                      const int* __restrict__ off, const int* __restrict__ eids,
                      const float* __restrict__ We, const float* __restrict__ be,
                      float* __restrict__ agg)
{
    const int n = blockIdx.x;
    const int d = threadIdx.x;   // 128
    const float w00 = We[d],           w01 = We[128 + d],       bb0 = be[d];
    const float w10 = We[256 + d],     w11 = We[256 + 128 + d], bb1 = be[128 + d];
    const float w20 = We[512 + d],     w21 = We[512 + 128 + d], bb2 = be[256 + d];
    const int beg = off[n], end = off[n + 1];
    float acc0 = 0.f, acc1 = 0.f, acc2 = 0.f;
    for (int i = beg; i < end; ++i) {
        int e = eids[i];
        int s = src[e];
        float ea0 = ea[2 * e], ea1 = ea[2 * e + 1];
        float xv = x[s * DD + d];
        acc0 += xv * sigm(ea0 * w00 + ea1 * w01 + bb0);
        acc1 += xv * sigm(ea0 * w10 + ea1 * w11 + bb1);
        acc2 += xv * sigm(ea0 * w20 + ea1 * w21 + bb2);
    }
    agg[              n * DD + d] = acc0;
    agg[N_NODES * DD + n * DD + d] = acc1;
    agg[2 * N_NODES * DD + n * DD + d] = acc2;
}

// ---------------- K3: xs_i = relu((x+agg_i)@Wx_i + bx_i), in-place over agg ----
__global__ void k_xs(const float* __restrict__ x, float* __restrict__ agg,
                     const float* __restrict__ Wx, const float* __restrict__ bx)
{
    const int i  = blockIdx.y;
    const int n0 = blockIdx.x * 16;
    const int j  = threadIdx.x;  // 128
    __shared__ float inL[16 * 128];
    float* aggi = agg + i * (N_NODES * DD);
    #pragma unroll
    for (int r = 0; r < 16; ++r)
        inL[r * 128 + j] = x[(n0 + r) * DD + j] + aggi[(n0 + r) * DD + j];
    __syncthreads();
    float acc[16];
    #pragma unroll
    for (int r = 0; r < 16; ++r) acc[r] = 0.f;
    const float* W = Wx + i * (DD * DD);
    for (int k = 0; k < 128; ++k) {
        float w = W[k * 128 + j];
        #pragma unroll
        for (int r = 0; r < 16; ++r) acc[r] += inL[r * 128 + k] * w;
    }
    float bb = bx[i * 128 + j];
    #pragma unroll
    for (int r = 0; r < 16; ++r) {
        float v = acc[r] + bb;
        aggi[(n0 + r) * DD + j] = v > 0.f ? v : 0.f;
    }
}

// ---------------- K4: P0 = xp @ wm_w0[:160] + b0  (step-invariant) ------------
__global__ void k_p0(const float* __restrict__ x, const float* __restrict__ lpe,
                     const float* __restrict__ rwse, const float* __restrict__ w0,
                     const float* __restrict__ b0, float* __restrict__ P0)
{
    const int n0 = blockIdx.x * 16;
    const int j  = threadIdx.x;  // 192
    __shared__ float inL[16 * 160];
    for (int idx = j; idx < 16 * 160; idx += 192) {
        int r = idx / 160, k = idx - r * 160;
        int n = n0 + r;
        float v;
        if (k < 128)      v = x[n * 128 + k];
        else if (k < 144) v = lpe[n * 16 + (k - 128)];
        else              v = rwse[n * 16 + (k - 144)];
        inL[idx] = v;
    }
    __syncthreads();
    if (j < 160) {
        float acc[16];
        #pragma unroll
        for (int r = 0; r < 16; ++r) acc[r] = 0.f;
        for (int k = 0; k < 160; ++k) {
            float w = w0[k * 160 + j];
            #pragma unroll
            for (int r = 0; r < 16; ++r) acc[r] += inL[r * 160 + k] * w;
        }
        float bb = b0[j];
        #pragma unroll
        for (int r = 0; r < 16; ++r) P0[(n0 + r) * 160 + j] = acc[r] + bb;
    }
}

// ---------------- K6: per-row MLP via bf16 MFMA -> attention scores -----------
__global__ __launch_bounds__(64) void k_mlp(
        const float* __restrict__ P0, const float* __restrict__ hw0,
        const unsigned short* __restrict__ w1T, const float* __restrict__ b1,
        const unsigned short* __restrict__ w2T, const float* __restrict__ b2,
        const float* __restrict__ w3, const float* __restrict__ b3,
        float* __restrict__ scores)
{
    const int n0  = blockIdx.x * 16;
    const int b   = n0 / MAXN_;      // 16 | 768 -> uniform
    const int l   = threadIdx.x;     // 64
    const int col = l & 15, q = l >> 4;
    __shared__ unsigned short A1[16 * 168];
    __shared__ unsigned short A2[16 * 168];

    // stage a1 = relu(P0 + hw0[b]) as bf16 [m][k]
    for (int idx = l; idx < 2560; idx += 64) {
        int m = idx / 160, k = idx - m * 160;
        float v = P0[(n0 + m) * 160 + k] + hw0[b * 160 + k];
        A1[m * 168 + k] = f2bf(v > 0.f ? v : 0.f);
    }
    __syncthreads();

    // ---- layer 1: a2 = relu(a1 @ w1 + b1) -> A2 ----
    for (int tile = 0; tile < 10; ++tile) {
        int c0 = tile * 16;
        f32x4 acc = {0.f, 0.f, 0.f, 0.f};
        #pragma unroll
        for (int ks = 0; ks < 5; ++ks) {
            bf16x8 af = *(const bf16x8*)&A1[col * 168 + ks * 32 + q * 8];
            bf16x8 bf = *(const bf16x8*)&w1T[(c0 + col) * 168 + ks * 32 + q * 8];
            acc = __builtin_amdgcn_mfma_f32_16x16x32_bf16(af, bf, acc, 0, 0, 0);
        }
        float bb = b1[c0 + col];
        #pragma unroll
        for (int r = 0; r < 4; ++r) {
            float v = acc[r] + bb;
            A2[(q * 4 + r) * 168 + c0 + col] = f2bf(v > 0.f ? v : 0.f);
        }
    }
    __syncthreads();

    // ---- layer 2 + fused score ----
    float p[4] = {0.f, 0.f, 0.f, 0.f};
    for (int tile = 0; tile < 10; ++tile) {
        int c0 = tile * 16;
        f32x4 acc = {0.f, 0.f, 0.f, 0.f};
        #pragma unroll
        for (int ks = 0; ks < 5; ++ks) {
            bf16x8 af = *(const bf16x8*)&A2[col * 168 + ks * 32 + q * 8];
            bf16x8 bf = *(const bf16x8*)&w2T[(c0 + col) * 168 + ks * 32 + q * 8];
            acc = __builtin_amdgcn_mfma_f32_16x16x32_bf16(af, bf, acc, 0, 0, 0);
        }
        float bb = b2[c0 + col];
        float wv = w3[c0 + col];
        #pragma unroll
        for (int r = 0; r < 4; ++r) {
            float v = acc[r] + bb;
            v = v > 0.f ? v : 0.f;
            p[r] += v * wv;
        }
    }
    #pragma unroll
    for (int m = 1; m <= 8; m <<= 1)
        #pragma unroll
        for (int r = 0; r < 4; ++r) p[r] += __shfl_xor(p[r], m);
    if (col == 0) {
        float bb = b3[0];
        #pragma unroll
        for (int r = 0; r < 4; ++r) scores[n0 + q * 4 + r] = p[r] + bb;
    }
}

// ---------------- K7: per-graph softmax + t + GRU + hw0_next (640 thr) --------
__global__ void k_graph(const float* __restrict__ scores,
                        const float* __restrict__ x, const float* __restrict__ lpe,
                        const float* __restrict__ rwse,
                        const float* __restrict__ Wi, const float* __restrict__ Wh,
                        const float* __restrict__ bi, const float* __restrict__ bh,
                        const float* __restrict__ w0h,
                        float* __restrict__ h, float* __restrict__ hw0,
                        float* __restrict__ tok, int step)
{
    const int b   = blockIdx.x;
    const int tid = threadIdx.x;  // 640
    __shared__ float eL[MAXN_];
    __shared__ float tpart[4][160];
    __shared__ float tL[160];
    __shared__ float hL[160];
    __shared__ float hN[160];
    __shared__ float red[10];
    const float inv_sqrt_d = 0.08838834764831845f;  // 128^-0.5

    float m = -1e30f;
    for (int i = tid; i < MAXN_; i += 640) {
        float q = scores[b * MAXN_ + i] * inv_sqrt_d;
        eL[i] = q;
        m = fmaxf(m, q);
    }
    m = blkMax(m, red);
    float s = 0.f;
    for (int i = tid; i < MAXN_; i += 640) {
        float e = __expf(eL[i] - m);
        eL[i] = e;
        s += e;
    }
    if (tid < 160) hL[tid] = h[b * 160 + tid];
    float S = blkSum(s, red);
    float scale = 1.f / (S * (float)MAXN_);
    // t partials: thread = (c, chunk); chunk covers 192 nodes
    {
        int c = tid % 160, chunk = tid / 160;
        float acc = 0.f;
        int i1 = chunk * 192 + 192;
        for (int i = chunk * 192; i < i1; ++i) {
            int n = b * MAXN_ + i;
            float v;
            if (c < 128)      v = x[n * 128 + c];
            else if (c < 144) v = lpe[n * 16 + (c - 128)];
            else              v = rwse[n * 16 + (c - 144)];
            acc += eL[i] * v;
        }
        tpart[chunk][c] = acc;
    }
    __syncthreads();
    if (tid < 160) {
        float tv = (tpart[0][tid] + tpart[1][tid] + tpart[2][tid] + tpart[3][tid]) * scale;
        tL[tid] = tv;
        tok[b * 640 + step * 160 + tid] = tv;
    }
    __syncthreads();
    // GRU
    if (tid < 160) {
        const int c = tid;
        float gr = bi[c], gz = bi[160 + c], gn = bi[320 + c];
        float hr = bh[c], hz = bh[160 + c], hn = bh[320 + c];
        for (int k = 0; k < 160; ++k) {
            float tv = tL[k], hv = hL[k];
            gr += tv * Wi[k * 480 + c];
            gz += tv * Wi[k * 480 + 160 + c];
            gn += tv * Wi[k * 480 + 320 + c];
            hr += hv * Wh[k * 480 + c];
            hz += hv * Wh[k * 480 + 160 + c];
            hn += hv * Wh[k * 480 + 320 + c];
        }
        float r = sigm(gr + hr);
        float z = sigm(gz + hz);
        float n = tanhf(gn + r * hn);
        float hnew = (1.f - z) * n + z * hL[c];
        hN[c] = hnew;
        h[b * 160 + c] = hnew;
    }
    __syncthreads();
    // hw0_next = h_new @ wm_w0[160:,:]
    if (tid < 160) {
        const int j = tid;
        float acc = 0.f;
        for (int k = 0; k < 160; ++k) acc += hN[k] * w0h[k * 160 + j];
        hw0[b * 160 + j] = acc;
    }
}

// ---------------- K9: mamba-ish part, one block per graph, t=3 output only ----
__global__ void k_mamba(const float* __restrict__ tok,
                        const float* __restrict__ Win, const float* __restrict__ convw,
                        const float* __restrict__ convb,
                        const float* __restrict__ Wx, const float* __restrict__ Wdt,
                        const float* __restrict__ bdt,
                        const float* __restrict__ Alog, const float* __restrict__ Dp,
                        const float* __restrict__ Wout,
                        const float* __restrict__ lng, const float* __restrict__ lnb,
                        float* __restrict__ mo_last)
{
    const int b   = blockIdx.x;
    const int tid = threadIdx.x;  // 256
    __shared__ float tokL[640];
    __shared__ float xpre[1280];
    __shared__ float xmL[1280];
    __shared__ float z3L[320];
    __shared__ float dtrL[40];
    __shared__ float BmL[512];
    __shared__ float Cm3L[128];
    __shared__ float dtL[1280];
    __shared__ float y3L[320];
    __shared__ float moL[160];
    __shared__ float red[8];

    for (int i = tid; i < 640; i += 256) tokL[i] = tok[b * 640 + i];
    __syncthreads();
    for (int o = tid; o < 1280; o += 256) {
        int t = o / 320, d = o - t * 320;
        float acc = 0.f;
        for (int k = 0; k < 160; ++k) acc += tokL[t * 160 + k] * Win[k * 640 + d];
        xpre[o] = acc;
    }
    for (int d = tid; d < 320; d += 256) {
        float acc = 0.f;
        for (int k = 0; k < 160; ++k) acc += tokL[480 + k] * Win[k * 640 + 320 + d];
        z3L[d] = acc;
    }
    __syncthreads();
    for (int o = tid; o < 1280; o += 256) {
        int t = o / 320, d = o - t * 320;
        float acc = convb[d];
        #pragma unroll
        for (int k = 0; k < 4; ++k) {
            int tt = t + k - 3;
            if (tt >= 0) acc += xpre[tt * 320 + d] * convw[d * 4 + k];
        }
        xmL[o] = acc * sigm(acc);
    }
    __syncthreads();
    for (int o = tid; o < 680; o += 256) {
        int t, col;
        if (o < 40)       { t = o / 10; col = o - t * 10; }
        else if (o < 552) { int i = o - 40; t = i >> 7; col = 10 + (i & 127); }
        else              { t = 3; col = 138 + (o - 552); }
        float acc = 0.f;
        for (int k = 0; k < 320; ++k) acc += xmL[t * 320 + k] * Wx[k * 266 + col];
        if (o < 40)       dtrL[o] = acc;
        else if (o < 552) BmL[o - 40] = acc;
        else              Cm3L[o - 552] = acc;
    }
    __syncthreads();
    for (int o = tid; o < 1280; o += 256) {
        int t = o / 320, d = o - t * 320;
        float acc = bdt[d];
        #pragma unroll
        for (int r = 0; r < 10; ++r) acc += dtrL[t * 10 + r] * Wdt[r * 320 + d];
        dtL[o] = softplusf(acc);
    }
    __syncthreads();
    {
        int w = tid >> 6, lane = tid & 63;
        for (int dbase = 0; dbase < 320; dbase += 4) {
            int d = dbase + w;
            float A0 = -__expf(Alog[d * 128 + lane]);
            float A1 = -__expf(Alog[d * 128 + 64 + lane]);
            float s0 = 0.f, s1 = 0.f;
            #pragma unroll
            for (int t = 0; t < 4; ++t) {
                float dtv = dtL[t * 320 + d];
                float xv  = xmL[t * 320 + d];
                float c0  = dtv * xv;
                s0 = s0 * __expf(dtv * A0) + c0 * BmL[t * 128 + lane];
                s1 = s1 * __expf(dtv * A1) + c0 * BmL[t * 128 + 64 + lane];
            }
            float contrib = s0 * Cm3L[lane] + s1 * Cm3L[64 + lane];
            #pragma unroll
            for (int off = 32; off > 0; off >>= 1) contrib += __shfl_down(contrib, off);
            if (lane == 0) {
                float y  = contrib + Dp[d] * xmL[3 * 320 + d];
                float zz = z3L[d];
                y3L[d] = y * (zz * sigm(zz));
            }
        }
    }
    __syncthreads();
    if (tid < 160) {
        float acc = 0.f;
        for (int d = 0; d < 320; ++d) acc += y3L[d] * Wout[d * 160 + tid];
        moL[tid] = acc;
    }
    float v  = (tid < 160) ? moL[tid] : 0.f;
    float sm = blkSum(v, red);
    float sq = blkSum(v * v, red);
    float mu  = sm / 160.f;
    float var = sq / 160.f - mu * mu;
    if (tid < 160)
        mo_last[b * 160 + tid] = (moL[tid] - mu) * rsqrtf(var + 1e-5f) * lng[tid] + lnb[tid];
}

// ---------------- K10 helpers: chunked staging for k_final --------------------
__device__ __forceinline__ void fin_load(float stg[17], int jj, int n0, int l,
                                         const float* __restrict__ xs,
                                         const float* __restrict__ mo_last,
                                         const int* __restrict__ batch) {
    int base = 136 * jj;
    #pragma unroll
    for (int t = 0; t < 17; ++t) {
        int idx = t * 64 + l;
        int r = idx & 7, k = base + (idx >> 3);
        stg[t] = (k < 384)
            ? xs[(k >> 7) * (N_NODES * 128) + (n0 + r) * 128 + (k & 127)]
            : mo_last[batch[n0 + r] * 160 + (k - 384)];
    }
}

// ---------------- K10: merge MLP + two LayerNorms -> out (R5/R6-proven fp32) --
__global__ __launch_bounds__(64) void k_final(
        const float* __restrict__ x, const float* __restrict__ xs,
        const int* __restrict__ batch, const float* __restrict__ mo_last,
        const float* __restrict__ w0, const float* __restrict__ b0,
        const float* __restrict__ g0, const float* __restrict__ beta0,
        const float* __restrict__ w1, const float* __restrict__ b1,
        const float* __restrict__ lng, const float* __restrict__ lnb,
        float* __restrict__ out)
{
    const int n0 = blockIdx.x * 8;
    const int l  = threadIdx.x;      // 64
    const int c0 = l * 2;
    __shared__ float catC[2][136 * 8];  // [chunk][kk][r]
    __shared__ float hmR[8 * 128];      // [r][k]

    float stg[17];
    float acc[8][2];
    #pragma unroll
    for (int r = 0; r < 8; ++r) { acc[r][0] = 0.f; acc[r][1] = 0.f; }

    fin_load(stg, 0, n0, l, xs, mo_last, batch);
    #pragma unroll
    for (int t = 0; t < 17; ++t) catC[0][t * 64 + l] = stg[t];
    fin_load(stg, 1, n0, l, xs, mo_last, batch);
    __syncthreads();

    // ---- GEMM1 over 4 chunks ----
    for (int j = 0; j < 4; ++j) {
        const float* buf = catC[j & 1];
        const float* wp  = w0 + (size_t)(j * 136) * 128 + c0;
        #pragma unroll 4
        for (int kk = 0; kk < 136; ++kk) {
            float4 ca = *(const float4*)&buf[kk * 8];
            float4 cb = *(const float4*)&buf[kk * 8 + 4];
            float2 w  = *(const float2*)&wp[kk * 128];
            float cr[8] = {ca.x, ca.y, ca.z, ca.w, cb.x, cb.y, cb.z, cb.w};
            #pragma unroll
            for (int r = 0; r < 8; ++r) {
                acc[r][0] += cr[r] * w.x;
                acc[r][1] += cr[r] * w.y;
            }
        }
        if (j < 3) {
            #pragma unroll
            for (int t = 0; t < 17; ++t) catC[(j + 1) & 1][t * 64 + l] = stg[t];
            if (j < 2) fin_load(stg, j + 2, n0, l, xs, mo_last, batch);
        }
        __syncthreads();
    }

    // ---- LN1 + relu (per row over 128 cols), write hmR ----
    {
        float2 bv = *(const float2*)&b0[c0];
        float2 gv = *(const float2*)&g0[c0];
        float2 tv = *(const float2*)&beta0[c0];
        float rs[8], rq[8];
        #pragma unroll
        for (int r = 0; r < 8; ++r) {
            float v0 = acc[r][0] + bv.x;
            float v1 = acc[r][1] + bv.y;
            acc[r][0] = v0; acc[r][1] = v1;
            rs[r] = v0 + v1;
            rq[r] = v0 * v0 + v1 * v1;
        }
        #pragma unroll
        for (int m = 1; m <= 32; m <<= 1)
            #pragma unroll
            for (int r = 0; r < 8; ++r) {
                rs[r] += __shfl_xor(rs[r], m);
                rq[r] += __shfl_xor(rq[r], m);
            }
        #pragma unroll
        for (int r = 0; r < 8; ++r) {
            float mu  = rs[r] * (1.f / 128.f);
            float var = rq[r] * (1.f / 128.f) - mu * mu;
            float rv  = rsqrtf(var + 1e-5f);
            float n0v = (acc[r][0] - mu) * rv * gv.x + tv.x;
            float n1v = (acc[r][1] - mu) * rv * gv.y + tv.y;
            n0v = n0v > 0.f ? n0v : 0.f;
            n1v = n1v > 0.f ? n1v : 0.f;
            *(float2*)&hmR[r * 128 + c0] = make_float2(n0v, n1v);
        }
    }
    __syncthreads();

    // ---- GEMM2: acc2[r][c] = sum_k hm[r][k] * w1[k][c0+c] ----
    float acc2[8][2];
    #pragma unroll
    for (int r = 0; r < 8; ++r) { acc2[r][0] = 0.f; acc2[r][1] = 0.f; }
    #pragma unroll 2
    for (int k = 0; k < 128; ++k) {
        float2 w = *(const float2*)&w1[k * 128 + c0];
        float hr[8];
        #pragma unroll
        for (int r = 0; r < 8; ++r) hr[r] = hmR[r * 128 + k];
        #pragma unroll
        for (int r = 0; r < 8; ++r) {
            acc2[r][0] += hr[r] * w.x;
            acc2[r][1] += hr[r] * w.y;
        }
    }

    // ---- residual + LN2 + store ----
    {
        float2 bv = *(const float2*)&b1[c0];
        float2 gv = *(const float2*)&lng[c0];
        float2 tv = *(const float2*)&lnb[c0];
        float rs[8], rq[8];
        #pragma unroll
        for (int r = 0; r < 8; ++r) {
            float2 xv = *(const float2*)&x[(n0 + r) * 128 + c0];
            float v0 = acc2[r][0] + bv.x + xv.x;
            float v1 = acc2[r][1] + bv.y + xv.y;
            acc2[r][0] = v0; acc2[r][1] = v1;
            rs[r] = v0 + v1;
            rq[r] = v0 * v0 + v1 * v1;
        }
        #pragma unroll
        for (int m = 1; m <= 32; m <<= 1)
            #pragma unroll
            for (int r = 0; r < 8; ++r) {
                rs[r] += __shfl_xor(rs[r], m);
                rq[r] += __shfl_xor(rq[r], m);
            }
        #pragma unroll
        for (int r = 0; r < 8; ++r) {
            float mu  = rs[r] * (1.f / 128.f);
            float var = rq[r] * (1.f / 128.f) - mu * mu;
            float rv  = rsqrtf(var + 1e-5f);
            float o0 = (acc2[r][0] - mu) * rv * gv.x + tv.x;
            float o1 = (acc2[r][1] - mu) * rv * gv.y + tv.y;
            *(float2*)&out[(n0 + r) * 128 + c0] = make_float2(o0, o1);
        }
    }
}

extern "C" void kernel_launch(void* const* d_in, const int* in_sizes, int n_in,
                              void* d_out, int out_size, void* d_ws, size_t ws_size,
                              hipStream_t stream) {
    const float* x     = (const float*)d_in[0];
    const float* ea    = (const float*)d_in[1];
    const float* lpe   = (const float*)d_in[2];
    const float* rwse  = (const float*)d_in[3];
    const int*   ei    = (const int*)d_in[4];
    const int*   batch = (const int*)d_in[5];
    const float* We    = (const float*)d_in[6];
    const float* be    = (const float*)d_in[7];
    const float* Wx    = (const float*)d_in[8];
    const float* bx    = (const float*)d_in[9];
    const float* w0    = (const float*)d_in[10];
    const float* b0    = (const float*)d_in[11];
    const float* w1    = (const float*)d_in[12];
    const float* b1    = (const float*)d_in[13];
    const float* w2    = (const float*)d_in[14];
    const float* b2    = (const float*)d_in[15];
    const float* w3    = (const float*)d_in[16];
    const float* b3    = (const float*)d_in[17];
    const float* gWi   = (const float*)d_in[18];
    const float* gWh   = (const float*)d_in[19];
    const float* gbi   = (const float*)d_in[20];
    const float* gbh   = (const float*)d_in[21];
    const float* mWin  = (const float*)d_in[22];
    const float* mcw   = (const float*)d_in[23];
    const float* mcb   = (const float*)d_in[24];
    const float* mWx   = (const float*)d_in[25];
    const float* mWdt  = (const float*)d_in[26];
    const float* mbdt  = (const float*)d_in[27];
    const float* mAlog = (const float*)d_in[28];
    const float* mDp   = (const float*)d_in[29];
    const float* mWout = (const float*)d_in[30];
    const float* lnmg  = (const float*)d_in[31];
    const float* lnmb  = (const float*)d_in[32];
    const float* mgw0  = (const float*)d_in[33];
    const float* mgb0  = (const float*)d_in[34];
    const float* mgg0  = (const float*)d_in[35];
    const float* mgbt0 = (const float*)d_in[36];
    const float* mgw1  = (const float*)d_in[37];
    const float* mgb1  = (const float*)d_in[38];
    const float* lng   = (const float*)d_in[39];
    const float* lnb   = (const float*)d_in[40];
    float* out = (float*)d_out;

    // ws layout — EXACT R6-proven layout.
    float* ws     = (float*)d_ws;
    float* agg    = ws;                     // 3*N*128 = 18,874,368 floats
    float* P0     = agg + 18874368;         // N*160  =  7,864,320
    float* scores = P0 + 7864320;           // N
    float* hbuf   = scores + N_NODES;       // B*160
    float* hw0    = hbuf + 10240;           // B*160
    float* tokb   = hw0 + 10240;            // B*4*160
    float* mo     = tokb + 40960;           // B*160
    int*   cnt    = (int*)(mo + 10240);     // N ints
    int*   off    = cnt + N_NODES;          // N+1 ints
    int*   cursor = off + N_NODES + 1;      // N ints
    int*   eids   = cursor + N_NODES;       // E ints
    uintptr_t pb  = ((uintptr_t)(eids + NEDGE) + 15) & ~(uintptr_t)15;
    unsigned short* w1T = (unsigned short*)pb;     // 160*168 bf16
    unsigned short* w2T = w1T + 160 * 168;         // 160*168 bf16

    hipMemsetAsync(cnt, 0, (size_t)N_NODES * 4, stream);
    hipMemsetAsync(hbuf, 0, (size_t)20480 * 4, stream);  // h and hw0

    const int* src = ei;
    const int* dstp = ei + NEDGE;

    k_hist<<<NEDGE / 256, 256, 0, stream>>>(dstp, cnt);
    k_scan<<<1, 256, 0, stream>>>(cnt, off, cursor);
    k_scatter<<<NEDGE / 256, 256, 0, stream>>>(dstp, cursor, eids);
    k_cvt<<<200, 256, 0, stream>>>(w1, w2, w1T, w2T);
    k_agg<<<N_NODES, 128, 0, stream>>>(x, ea, src, off, eids, We, be, agg);

    dim3 g3(N_NODES / 16, 3);
    k_xs<<<g3, 128, 0, stream>>>(x, agg, Wx, bx);
    k_p0<<<N_NODES / 16, 192, 0, stream>>>(x, lpe, rwse, w0, b0, P0);
    for (int t = 0; t < 4; ++t) {
        k_mlp<<<N_NODES / 16, 64, 0, stream>>>(P0, hw0, w1T, b1, w2T, b2, w3, b3, scores);
        k_graph<<<BGRAPH, 640, 0, stream>>>(scores, x, lpe, rwse, gWi, gWh, gbi, gbh,
                                            w0 + 160 * 160, hbuf, hw0, tokb, t);
    }
    k_mamba<<<BGRAPH, 256, 0, stream>>>(tokb, mWin, mcw, mcb, mWx, mWdt, mbdt,
                                        mAlog, mDp, mWout, lnmg, lnmb, mo);
    k_final<<<N_NODES / 8, 64, 0, stream>>>(x, agg, batch, mo, mgw0, mgb0, mgg0, mgbt0,
                                            mgw1, mgb1, lng, lnb, out);
}